// Round 3
// baseline (699.793 us; speedup 1.0000x reference)
//
#include <hip/hip_runtime.h>
#include <cstdint>
#include <cstddef>

#define B_N   16
#define A_N   8732
#define C_N   91
#define FG_N  90
#define K_TOP 400
#define D_N   200
#define NTASK (B_N * FG_N)   // 1440
#define NW    7              // 448 bits >= K_TOP columns

// ---------------------------------------------------------------------------
// K1: per-anchor softmax (store fg probs transposed (B, 90, A)) + box decode
// ---------------------------------------------------------------------------
__global__ __launch_bounds__(256) void k1_softmax_decode(
    const float* __restrict__ cls, const float* __restrict__ reg,
    const float* __restrict__ anc, float* __restrict__ probs_t,
    float* __restrict__ boxes)
{
#pragma clang fp contract(off)
  int t = blockIdx.x * 256 + threadIdx.x;
  if (t >= B_N * A_N) return;
  int b = t / A_N;
  int a = t - b * A_N;
  const float* lg = cls + (size_t)t * C_N;
  float m = lg[0];
  for (int c = 1; c < C_N; ++c) m = fmaxf(m, lg[c]);
  float s = 0.0f;
  for (int c = 0; c < C_N; ++c) s += expf(lg[c] - m);
  for (int c = 1; c < C_N; ++c)
    probs_t[((size_t)b * FG_N + (c - 1)) * A_N + a] = expf(lg[c] - m) / s;

  float4 rl = *(const float4*)(reg + (size_t)t * 4);
  float4 an = *(const float4*)(anc + (size_t)a * 4);
  float wa = an.z - an.x;
  float ha = an.w - an.y;
  float cxa = an.x + 0.5f * wa;
  float cya = an.y + 0.5f * ha;
  float dx = rl.x / 10.0f;
  float dy = rl.y / 10.0f;
  const float clipv = 4.135166556742356f;   // log(1000/16)
  float dw = fminf(rl.z / 5.0f, clipv);
  float dh = fminf(rl.w / 5.0f, clipv);
  float t1 = dx * wa;  float cx = t1 + cxa;
  float t2 = dy * ha;  float cy = t2 + cya;
  float w = expf(dw) * wa;
  float h = expf(dh) * ha;
  float4 out;
  out.x = fminf(fmaxf(cx - 0.5f * w, 0.0f), 300.0f);
  out.y = fminf(fmaxf(cy - 0.5f * h, 0.0f), 300.0f);
  out.z = fminf(fmaxf(cx + 0.5f * w, 0.0f), 300.0f);
  out.w = fminf(fmaxf(cy + 0.5f * h, 0.0f), 300.0f);
  *(float4*)(boxes + (size_t)t * 4) = out;
}

// ---------------------------------------------------------------------------
// K2: exact top-400 per (image, fg-class) via 3-round radix select on float
//     bits + bitonic sort of candidates with (score desc, anchor asc) order.
// ---------------------------------------------------------------------------
__device__ __forceinline__ void scan_select(int* hist, int nbins, int need,
                                            int tid, int* chunk, int* res)
{
  int per = nbins >> 8;            // 4096 -> 16, 256 -> 1
  int s = 0;
  for (int i = 0; i < per; ++i) s += hist[tid * per + i];
  chunk[tid] = s;
  __syncthreads();
  if (tid == 0) {
    int cum = 0;
    for (int t2 = 255; t2 >= 0; --t2) { int v = chunk[t2]; chunk[t2] = cum; cum += v; }
  }
  __syncthreads();
  int cum = chunk[tid];            // count in strictly-higher chunks
  for (int i = per - 1; i >= 0; --i) {
    int bn = tid * per + i;
    int h = hist[bn];
    if (cum < need && need <= cum + h) { res[0] = bn; res[1] = cum; }
    cum += h;
  }
  __syncthreads();
}

__global__ __launch_bounds__(256) void k2_topk(
    const float* __restrict__ probs_t, int* __restrict__ topk_anchor,
    float* __restrict__ topk_score, int* __restrict__ topk_cnt)
{
  __shared__ int hist[4096];
  __shared__ int chunk[256];
  __shared__ int res[2];
  __shared__ int s_total;
  __shared__ int s_lcnt;
  __shared__ unsigned long long lst[1024];
  const int task = blockIdx.x;
  const int tid = threadIdx.x;
  const float* sc = probs_t + (size_t)task * A_N;

  for (int i = tid; i < 4096; i += 256) hist[i] = 0;
  __syncthreads();
  for (int a = tid; a < A_N; a += 256) {
    float p = sc[a];
    if (p > 0.01f) atomicAdd(&hist[__float_as_uint(p) >> 20], 1);
  }
  __syncthreads();
  { int s = 0;
    for (int i = tid; i < 4096; i += 256) s += hist[i];
    chunk[tid] = s; }
  __syncthreads();
  if (tid == 0) { int tot = 0; for (int i = 0; i < 256; ++i) tot += chunk[i]; s_total = tot; }
  __syncthreads();
  const int total = s_total;
  const int ksel = total < K_TOP ? total : K_TOP;
  unsigned cutoff = 1u;            // all valid keys (positive floats) >= 1
  if (total > K_TOP) {
    int need = K_TOP;
    scan_select(hist, 4096, need, tid, chunk, res);
    const unsigned b1 = (unsigned)res[0];
    need -= res[1];
    __syncthreads();
    for (int i = tid; i < 4096; i += 256) hist[i] = 0;
    __syncthreads();
    for (int a = tid; a < A_N; a += 256) {
      float p = sc[a];
      if (p > 0.01f) {
        unsigned k = __float_as_uint(p);
        if ((k >> 20) == b1) atomicAdd(&hist[(k >> 8) & 0xFFFu], 1);
      }
    }
    __syncthreads();
    scan_select(hist, 4096, need, tid, chunk, res);
    const unsigned b2 = (unsigned)res[0];
    need -= res[1];
    const unsigned pre12 = (b1 << 12) | b2;     // value of (key >> 8)
    __syncthreads();
    hist[tid] = 0;
    __syncthreads();
    for (int a = tid; a < A_N; a += 256) {
      float p = sc[a];
      if (p > 0.01f) {
        unsigned k = __float_as_uint(p);
        if ((k >> 8) == pre12) atomicAdd(&hist[k & 0xFFu], 1);
      }
    }
    __syncthreads();
    scan_select(hist, 256, need, tid, chunk, res);
    cutoff = (pre12 << 8) | (unsigned)res[0];
    __syncthreads();
  }
  if (tid == 0) s_lcnt = 0;
  __syncthreads();
  for (int a = tid; a < A_N; a += 256) {
    float p = sc[a];
    if (p > 0.01f) {
      unsigned k = __float_as_uint(p);
      if (k >= cutoff) {
        int pos = atomicAdd(&s_lcnt, 1);
        if (pos < 1024)
          lst[pos] = ((unsigned long long)k << 32) | (unsigned)(0xFFFFFFFFu - (unsigned)a);
      }
    }
  }
  __syncthreads();
  const int n = s_lcnt < 1024 ? s_lcnt : 1024;
  for (int i = tid; i < 1024; i += 256) if (i >= n) lst[i] = 0ULL;
  __syncthreads();
  // bitonic sort, descending; ties (same score) -> lower anchor first via ~a
  for (int kk = 2; kk <= 1024; kk <<= 1) {
    for (int jj = kk >> 1; jj > 0; jj >>= 1) {
      for (int i = tid; i < 1024; i += 256) {
        int ix = i ^ jj;
        if (ix > i) {
          unsigned long long va = lst[i], vb = lst[ix];
          bool desc = ((i & kk) == 0);
          if (desc ? (va < vb) : (va > vb)) { lst[i] = vb; lst[ix] = va; }
        }
      }
      __syncthreads();
    }
  }
  for (int r = tid; r < K_TOP; r += 256) {
    int anchor = 0;
    float scv = -1.0f;
    if (r < ksel) {
      unsigned long long v = lst[r];
      anchor = (int)(0xFFFFFFFFu - (unsigned)(v & 0xFFFFFFFFull));
      scv = __uint_as_float((unsigned)(v >> 32));
    }
    topk_anchor[(size_t)task * K_TOP + r] = anchor;
    topk_score[(size_t)task * K_TOP + r] = scv;
  }
  if (tid == 0) topk_cnt[task] = ksel;
}

// ---------------------------------------------------------------------------
// K3: bitmask NMS. One block per (image,class). Phase A: stage offset boxes +
//     areas in LDS. Phase B (parallel, throughput-bound): upper-triangular
//     suppression matrix, 64 lanes = 64 consecutive rows vs broadcast column.
//     IoU decision via guarded reciprocal: exact-division fallback only when
//     |q-0.45|<=1e-3 (rcp rel err ~1e-7), so decisions match reference
//     bit-exactly. Phase C (serial, cheap): bit-ops greedy with next-row
//     prefetch, removed-mask distributed over lanes 0..6 of wave 0.
// ---------------------------------------------------------------------------
__global__ __launch_bounds__(256) void k3_nms(
    const float* __restrict__ boxes, const int* __restrict__ topk_anchor,
    const float* __restrict__ topk_score, const int* __restrict__ topk_cnt,
    unsigned long long* __restrict__ kept_key, int* __restrict__ kept_cnt)
{
#pragma clang fp contract(off)
  __shared__ float4 cb[K_TOP];                    // 6.4 KB
  __shared__ float  car[K_TOP];                   // 1.6 KB
  __shared__ unsigned long long rowm[K_TOP][NW];  // 22.4 KB
  __shared__ int s_keptr[D_N];
  __shared__ int s_nk;
  const int task = blockIdx.x;
  const int tid  = threadIdx.x;
  const int b = task / FG_N;
  const int c = task - b * FG_N;
  const float off = (float)(c + 1) * 302.0f;
  const int cnt = topk_cnt[task];
  const int* ta = topk_anchor + (size_t)task * K_TOP;
  const float* ts = topk_score + (size_t)task * K_TOP;
  const float* bx = boxes + (size_t)b * (A_N * 4);

  // Phase A: stage candidates (offset applied) + areas
  for (int k = tid; k < cnt; k += 256) {
    int anchor = ta[k];
    float4 v = *(const float4*)(bx + (size_t)anchor * 4);
    v.x += off; v.y += off; v.z += off; v.w += off;
    cb[k] = v;
    car[k] = (v.z - v.x) * (v.w - v.y);
  }
  __syncthreads();

  // Phase B: suppression matrix. Wave-unit = (row-block of 64 rows, word w).
  const int RB = (cnt + 63) >> 6;                 // row blocks
  const int wave = tid >> 6, lane = tid & 63;
  for (int u = wave; u < RB * NW; u += 4) {
    int rb = u / NW, w = u - rb * NW;
    int i = rb * 64 + lane;                       // this lane's row
    int j0 = w * 64;
    int jend = j0 + 64 < cnt ? j0 + 64 : cnt;
    unsigned long long bits = 0;
    if (jend > rb * 64 + 1) {                     // any lane may have work
      float4 bi; float ai = 0.0f;
      bool rowok = (i < cnt);
      if (rowok) { bi = cb[i]; ai = car[i]; }
      for (int j = j0; j < jend; ++j) {           // broadcast column reads
        float4 bj = cb[j];
        float aj = car[j];
        if (rowok && j > i) {
          float ix1 = fmaxf(bi.x, bj.x);
          float iy1 = fmaxf(bi.y, bj.y);
          float ix2 = fminf(bi.z, bj.z);
          float iy2 = fminf(bi.w, bj.w);
          float inter = fmaxf(ix2 - ix1, 0.0f) * fmaxf(iy2 - iy1, 0.0f);
          float denom = ai + aj - inter + 1e-9f;
          float q = inter * __builtin_amdgcn_rcpf(denom);
          bool sup;
          if (fabsf(q - 0.45f) > 1e-3f) sup = q > 0.45f;
          else                          sup = (inter / denom) > 0.45f;  // exact ref expr
          if (sup) bits |= 1ull << (j - j0);
        }
      }
    }
    if (i < cnt) rowm[i][w] = bits;
  }
  __syncthreads();

  // Phase C: serial greedy via bitmask, wave 0 only. Lane l<NW owns removed
  // word l. Keep decision is wave-uniform (broadcast via shfl).
  if (tid < 64) {
    unsigned long long rm = 0;
    int nk = 0;
    unsigned long long currow = (lane < NW && cnt > 0) ? rowm[0][lane] : 0ULL;
    for (int r = 0; r < cnt; ++r) {
      unsigned long long nxtrow =
          (lane < NW && r + 1 < cnt) ? rowm[r + 1][lane] : 0ULL;  // prefetch
      unsigned long long wv = __shfl(rm, r >> 6, 64);
      if (!((wv >> (r & 63)) & 1ULL)) {
        if (lane == 0) s_keptr[nk] = r;
        rm |= currow;
        ++nk;
        if (nk == D_N) break;
      }
      currow = nxtrow;
    }
    if (lane == 0) s_nk = nk;
  }
  __syncthreads();

  const int nk = s_nk;
  for (int k = tid; k < nk; k += 256) {
    int r = s_keptr[k];
    unsigned sb = __float_as_uint(ts[r]);
    kept_key[(size_t)task * D_N + k] =
        ((unsigned long long)sb << 32) |
        (unsigned)(0xFFFFFFFFu - (unsigned)(c * K_TOP + r));
  }
  if (tid == 0) kept_cnt[task] = nk;
}

// ---------------------------------------------------------------------------
// K4: per-image 90-way merge of sorted per-class survivor lists -> global
//     top-200 pick sequence. One wave per image; heads prefetched 2 deep so
//     consecutive same-class wins don't stall on L2 latency.
// ---------------------------------------------------------------------------
__global__ __launch_bounds__(64) void k4_merge(
    const unsigned long long* __restrict__ kept_key,
    const int* __restrict__ kept_cnt, int* __restrict__ pick_flat)
{
  int b = blockIdx.x;
  int lane = threadIdx.x;
  int c0 = lane, c1 = 64 + lane;
  int base0 = b * FG_N + c0;
  int base1 = b * FG_N + c1;
  int cnt0 = (c0 < FG_N) ? kept_cnt[base0] : 0;
  int cnt1 = (c1 < FG_N) ? kept_cnt[base1] : 0;
  const unsigned long long* kk0 = kept_key + (size_t)base0 * D_N;
  const unsigned long long* kk1 = kept_key + (size_t)base1 * D_N;
  int h0 = 0, h1 = 0;
  unsigned long long cur0 = cnt0 > 0 ? kk0[0] : 0ULL;
  unsigned long long n0a  = cnt0 > 1 ? kk0[1] : 0ULL;
  unsigned long long n0b  = cnt0 > 2 ? kk0[2] : 0ULL;
  unsigned long long cur1 = cnt1 > 0 ? kk1[0] : 0ULL;
  unsigned long long n1a  = cnt1 > 1 ? kk1[1] : 0ULL;
  unsigned long long n1b  = cnt1 > 2 ? kk1[2] : 0ULL;
  for (int i = 0; i < D_N; ++i) {
    unsigned long long m = cur0 > cur1 ? cur0 : cur1;
#pragma unroll
    for (int d = 1; d < 64; d <<= 1) {
      unsigned long long o = __shfl_xor(m, d, 64);
      if (o > m) m = o;
    }
    if (m == 0ULL) {
      if (lane == 0) pick_flat[b * D_N + i] = -1;
    } else {
      unsigned flat = 0xFFFFFFFFu - (unsigned)(m & 0xFFFFFFFFull);
      if (lane == 0) pick_flat[b * D_N + i] = (int)flat;
      int cw = (int)(flat / K_TOP);
      if (cw == c0) {
        ++h0; cur0 = n0a; n0a = n0b;
        n0b = (h0 + 2 < cnt0) ? kk0[h0 + 2] : 0ULL;
      } else if (cw == c1) {
        ++h1; cur1 = n1a; n1a = n1b;
        n1b = (h1 + 2 < cnt1) ? kk1[h1 + 2] : 0ULL;
      }
    }
  }
}

// ---------------------------------------------------------------------------
// K5: emit boxes / top-2 scores / labels per pick (zeros for invalid picks).
// ---------------------------------------------------------------------------
__global__ __launch_bounds__(256) void k5_output(
    const float* __restrict__ probs_t, const float* __restrict__ boxes,
    const int* __restrict__ topk_anchor, const int* __restrict__ pick_flat,
    float* __restrict__ out)
{
  int t = blockIdx.x * 256 + threadIdx.x;
  if (t >= B_N * D_N) return;
  int b = t / D_N;
  float* ob = out + (size_t)t * 4;
  float* os = out + (size_t)B_N * D_N * 4 + (size_t)t * 2;
  float* ol = out + (size_t)B_N * D_N * 6 + (size_t)t * 2;
  int flat = pick_flat[t];
  if (flat < 0) {
    ob[0] = 0.0f; ob[1] = 0.0f; ob[2] = 0.0f; ob[3] = 0.0f;
    os[0] = 0.0f; os[1] = 0.0f;
    ol[0] = 0.0f; ol[1] = 0.0f;
    return;
  }
  int c = flat / K_TOP;
  int r = flat - c * K_TOP;
  int anchor = topk_anchor[((size_t)b * FG_N + c) * K_TOP + r];
  const float* bp = boxes + ((size_t)b * A_N + anchor) * 4;
  ob[0] = bp[0]; ob[1] = bp[1]; ob[2] = bp[2]; ob[3] = bp[3];
  float v1 = -1.0f; int i1 = 0;
  float v2 = -1.0f; int i2 = 0;
  const float* pp = probs_t + (size_t)b * FG_N * A_N + anchor;
  for (int cc = 0; cc < FG_N; ++cc) {
    float p = pp[(size_t)cc * A_N];
    if (p > v1)      { v2 = v1; i2 = i1; v1 = p; i1 = cc; }
    else if (p > v2) { v2 = p; i2 = cc; }
  }
  os[0] = v1; os[1] = v2;
  ol[0] = (float)(i1 + 1); ol[1] = (float)(i2 + 1);
}

// ---------------------------------------------------------------------------
extern "C" void kernel_launch(void* const* d_in, const int* in_sizes, int n_in,
                              void* d_out, int out_size, void* d_ws, size_t ws_size,
                              hipStream_t stream)
{
  (void)in_sizes; (void)n_in; (void)out_size; (void)ws_size;
  const float* cls = (const float*)d_in[0];
  const float* reg = (const float*)d_in[1];
  const float* anc = (const float*)d_in[2];

  char* w = (char*)d_ws;
  size_t off = 0;
  auto carve = [&](size_t bytes) -> char* {
    char* p = w + off;
    off += (bytes + 255) & ~(size_t)255;
    return p;
  };
  float* probs_t                = (float*)carve((size_t)B_N * FG_N * A_N * 4);
  float* boxes                  = (float*)carve((size_t)B_N * A_N * 4 * 4);
  int* topk_anchor              = (int*)carve((size_t)NTASK * K_TOP * 4);
  float* topk_score             = (float*)carve((size_t)NTASK * K_TOP * 4);
  int* topk_cnt                 = (int*)carve((size_t)NTASK * 4);
  unsigned long long* kept_key  = (unsigned long long*)carve((size_t)NTASK * D_N * 8);
  int* kept_cnt                 = (int*)carve((size_t)NTASK * 4);
  int* pick_flat                = (int*)carve((size_t)B_N * D_N * 4);

  hipLaunchKernelGGL(k1_softmax_decode, dim3((B_N * A_N + 255) / 256), dim3(256), 0, stream,
                     cls, reg, anc, probs_t, boxes);
  hipLaunchKernelGGL(k2_topk, dim3(NTASK), dim3(256), 0, stream,
                     probs_t, topk_anchor, topk_score, topk_cnt);
  hipLaunchKernelGGL(k3_nms, dim3(NTASK), dim3(256), 0, stream,
                     boxes, topk_anchor, topk_score, topk_cnt, kept_key, kept_cnt);
  hipLaunchKernelGGL(k4_merge, dim3(B_N), dim3(64), 0, stream,
                     kept_key, kept_cnt, pick_flat);
  hipLaunchKernelGGL(k5_output, dim3((B_N * D_N + 255) / 256), dim3(256), 0, stream,
                     probs_t, boxes, topk_anchor, pick_flat, (float*)d_out);
}

// Round 4
// 553.391 us; speedup vs baseline: 1.2646x; 1.2646x over previous
//
#include <hip/hip_runtime.h>
#include <cstdint>
#include <cstddef>

#define B_N   16
#define A_N   8732
#define C_N   91
#define FG_N  90
#define K_TOP 400
#define D_N   200
#define NTASK (B_N * FG_N)   // 1440

// ---------------------------------------------------------------------------
// K1: per-anchor softmax (store fg probs transposed (B, 90, A)) + box decode
// ---------------------------------------------------------------------------
__global__ __launch_bounds__(256) void k1_softmax_decode(
    const float* __restrict__ cls, const float* __restrict__ reg,
    const float* __restrict__ anc, float* __restrict__ probs_t,
    float* __restrict__ boxes)
{
#pragma clang fp contract(off)
  int t = blockIdx.x * 256 + threadIdx.x;
  if (t >= B_N * A_N) return;
  int b = t / A_N;
  int a = t - b * A_N;
  const float* lg = cls + (size_t)t * C_N;
  float m = lg[0];
  for (int c = 1; c < C_N; ++c) m = fmaxf(m, lg[c]);
  float s = 0.0f;
  for (int c = 0; c < C_N; ++c) s += expf(lg[c] - m);
  for (int c = 1; c < C_N; ++c)
    probs_t[((size_t)b * FG_N + (c - 1)) * A_N + a] = expf(lg[c] - m) / s;

  float4 rl = *(const float4*)(reg + (size_t)t * 4);
  float4 an = *(const float4*)(anc + (size_t)a * 4);
  float wa = an.z - an.x;
  float ha = an.w - an.y;
  float cxa = an.x + 0.5f * wa;
  float cya = an.y + 0.5f * ha;
  float dx = rl.x / 10.0f;
  float dy = rl.y / 10.0f;
  const float clipv = 4.135166556742356f;   // log(1000/16)
  float dw = fminf(rl.z / 5.0f, clipv);
  float dh = fminf(rl.w / 5.0f, clipv);
  float t1 = dx * wa;  float cx = t1 + cxa;
  float t2 = dy * ha;  float cy = t2 + cya;
  float w = expf(dw) * wa;
  float h = expf(dh) * ha;
  float4 out;
  out.x = fminf(fmaxf(cx - 0.5f * w, 0.0f), 300.0f);
  out.y = fminf(fmaxf(cy - 0.5f * h, 0.0f), 300.0f);
  out.z = fminf(fmaxf(cx + 0.5f * w, 0.0f), 300.0f);
  out.w = fminf(fmaxf(cy + 0.5f * h, 0.0f), 300.0f);
  *(float4*)(boxes + (size_t)t * 4) = out;
}

// ---------------------------------------------------------------------------
// K2: exact top-400 per (image, fg-class) via radix select on float bits.
//     Round-1 early exit: if survivors at the 12-bit-coarse cutoff fit in the
//     1024-slot sort buffer (virtually always: ~3.4 keys/bin), skip rounds
//     2-3 entirely (saves 2 global passes + 2 serial scans). Coarse cutoff
//     b1<<20 selects the identical top-400 set (bin is monotone in key).
//     Dynamic bitonic width 512/1024 by survivor count.
// ---------------------------------------------------------------------------
__device__ __forceinline__ void scan_select(int* hist, int nbins, int need,
                                            int tid, int* chunk, int* res)
{
  int per = nbins >> 8;            // 4096 -> 16, 256 -> 1
  int s = 0;
  for (int i = 0; i < per; ++i) s += hist[tid * per + i];
  chunk[tid] = s;
  __syncthreads();
  if (tid == 0) {
    int cum = 0;
    for (int t2 = 255; t2 >= 0; --t2) { int v = chunk[t2]; chunk[t2] = cum; cum += v; }
  }
  __syncthreads();
  int cum = chunk[tid];            // count in strictly-higher chunks
  for (int i = per - 1; i >= 0; --i) {
    int bn = tid * per + i;
    int h = hist[bn];
    if (cum < need && need <= cum + h) { res[0] = bn; res[1] = cum; }
    cum += h;
  }
  __syncthreads();
}

__global__ __launch_bounds__(256) void k2_topk(
    const float* __restrict__ probs_t, int* __restrict__ topk_anchor,
    float* __restrict__ topk_score, int* __restrict__ topk_cnt)
{
  __shared__ int hist[4096];
  __shared__ int chunk[256];
  __shared__ int res[2];
  __shared__ int s_total;
  __shared__ int s_lcnt;
  __shared__ unsigned long long lst[1024];
  const int task = blockIdx.x;
  const int tid = threadIdx.x;
  const float* sc = probs_t + (size_t)task * A_N;

  for (int i = tid; i < 4096; i += 256) hist[i] = 0;
  __syncthreads();
  for (int a = tid; a < A_N; a += 256) {
    float p = sc[a];
    if (p > 0.01f) atomicAdd(&hist[__float_as_uint(p) >> 20], 1);
  }
  __syncthreads();
  { int s = 0;
    for (int i = tid; i < 4096; i += 256) s += hist[i];
    chunk[tid] = s; }
  __syncthreads();
  if (tid == 0) { int tot = 0; for (int i = 0; i < 256; ++i) tot += chunk[i]; s_total = tot; }
  __syncthreads();
  const int total = s_total;
  const int ksel = total < K_TOP ? total : K_TOP;
  unsigned cutoff = 1u;            // all valid keys (positive floats) >= 1
  if (total > K_TOP) {
    int need = K_TOP;
    scan_select(hist, 4096, need, tid, chunk, res);
    const unsigned b1 = (unsigned)res[0];
    const int above1 = res[1];
    const int in1 = hist[b1];                 // hist intact here
    __syncthreads();
    if (above1 + in1 <= 1024) {
      // Early exit: collect everything in bins >= b1 (fits in lst).
      cutoff = b1 << 20;
    } else {
      need -= above1;
      for (int i = tid; i < 4096; i += 256) hist[i] = 0;
      __syncthreads();
      for (int a = tid; a < A_N; a += 256) {
        float p = sc[a];
        if (p > 0.01f) {
          unsigned k = __float_as_uint(p);
          if ((k >> 20) == b1) atomicAdd(&hist[(k >> 8) & 0xFFFu], 1);
        }
      }
      __syncthreads();
      scan_select(hist, 4096, need, tid, chunk, res);
      const unsigned b2 = (unsigned)res[0];
      need -= res[1];
      const unsigned pre12 = (b1 << 12) | b2;     // value of (key >> 8)
      __syncthreads();
      hist[tid] = 0;
      __syncthreads();
      for (int a = tid; a < A_N; a += 256) {
        float p = sc[a];
        if (p > 0.01f) {
          unsigned k = __float_as_uint(p);
          if ((k >> 8) == pre12) atomicAdd(&hist[k & 0xFFu], 1);
        }
      }
      __syncthreads();
      scan_select(hist, 256, need, tid, chunk, res);
      cutoff = (pre12 << 8) | (unsigned)res[0];
      __syncthreads();
    }
  }
  if (tid == 0) s_lcnt = 0;
  __syncthreads();
  for (int a = tid; a < A_N; a += 256) {
    float p = sc[a];
    if (p > 0.01f) {
      unsigned k = __float_as_uint(p);
      if (k >= cutoff) {
        int pos = atomicAdd(&s_lcnt, 1);
        if (pos < 1024)
          lst[pos] = ((unsigned long long)k << 32) | (unsigned)(0xFFFFFFFFu - (unsigned)a);
      }
    }
  }
  __syncthreads();
  const int n = s_lcnt < 1024 ? s_lcnt : 1024;
  for (int i = tid; i < 1024; i += 256) if (i >= n) lst[i] = 0ULL;
  __syncthreads();
  const int W = (n <= 512) ? 512 : 1024;
  // bitonic sort, descending; ties impossible (keys distinct via ~anchor)
  for (int kk = 2; kk <= W; kk <<= 1) {
    for (int jj = kk >> 1; jj > 0; jj >>= 1) {
      for (int i = tid; i < W; i += 256) {
        int ix = i ^ jj;
        if (ix > i) {
          unsigned long long va = lst[i], vb = lst[ix];
          bool desc = ((i & kk) == 0);
          if (desc ? (va < vb) : (va > vb)) { lst[i] = vb; lst[ix] = va; }
        }
      }
      __syncthreads();
    }
  }
  for (int r = tid; r < K_TOP; r += 256) {
    int anchor = 0;
    float scv = -1.0f;
    if (r < ksel) {
      unsigned long long v = lst[r];
      anchor = (int)(0xFFFFFFFFu - (unsigned)(v & 0xFFFFFFFFull));
      scv = __uint_as_float((unsigned)(v >> 32));
    }
    topk_anchor[(size_t)task * K_TOP + r] = anchor;
    topk_score[(size_t)task * K_TOP + r] = scv;
  }
  if (tid == 0) topk_cnt[task] = ksel;
}

// ---------------------------------------------------------------------------
// K3: per-(image,class) serial greedy NMS, one wave per class (R2 structure).
//     Division-free IoU decision: inter/denom > 0.45  <=>  inter > 0.45*denom
//     (denom >= 1e-9 > 0). Relative guard band 1.5e-6 (>> combined 1-ulp
//     rounding of both forms) falls back to the bit-exact reference division,
//     so suppression decisions are provably identical to the reference.
//     Candidates staged in LDS with next-candidate prefetch; kept boxes in
//     distributed registers; kept_key written in parallel epilogue.
// ---------------------------------------------------------------------------
__global__ __launch_bounds__(256) void k3_nms(
    const float* __restrict__ boxes, const int* __restrict__ topk_anchor,
    const float* __restrict__ topk_score, const int* __restrict__ topk_cnt,
    unsigned long long* __restrict__ kept_key, int* __restrict__ kept_cnt)
{
#pragma clang fp contract(off)
  __shared__ float4 cbox[4][K_TOP];      // 25.6 KB
  const int wid  = threadIdx.x >> 6;
  const int lane = threadIdx.x & 63;
  const int task = blockIdx.x * 4 + wid; // grid is exactly NTASK/4
  const int b = task / FG_N;
  const int c = task - b * FG_N;
  const float off = (float)(c + 1) * 302.0f;
  const int cnt = topk_cnt[task];
  const int* ta = topk_anchor + (size_t)task * K_TOP;
  const float* ts = topk_score + (size_t)task * K_TOP;
  const float* bx = boxes + (size_t)b * (A_N * 4);

  for (int k = lane; k < cnt; k += 64) {
    int anchor = ta[k];
    float4 v = *(const float4*)(bx + (size_t)anchor * 4);
    v.x += off; v.y += off; v.z += off; v.w += off;
    cbox[wid][k] = v;
  }
  __syncthreads();

  float kx1[4], ky1[4], kx2[4], ky2[4], kar[4];
  int   kr[4];
  int nk = 0;
  if (cnt > 0) {
    float4 cur = cbox[wid][0];
    for (int r = 0; r < cnt; ++r) {
      int rn = (r + 1 < cnt) ? r + 1 : r;
      float4 nxt = cbox[wid][rn];          // prefetch, independent of append
      float area = (cur.z - cur.x) * (cur.w - cur.y);
      bool sup = false;
#pragma unroll
      for (int s = 0; s < 4; ++s) {
        int k = s * 64 + lane;
        if (k < nk) {
          float ix1 = fmaxf(cur.x, kx1[s]);
          float iy1 = fmaxf(cur.y, ky1[s]);
          float ix2 = fminf(cur.z, kx2[s]);
          float iy2 = fminf(cur.w, ky2[s]);
          float inter = fmaxf(ix2 - ix1, 0.0f) * fmaxf(iy2 - iy1, 0.0f);
          float denom = kar[s] + area - inter + 1e-9f;
          float thr = 0.45f * denom;
          bool s_sup = inter > thr;
          if (fabsf(inter - thr) <= 1.5e-6f * thr)      // ambiguous band: rare
            s_sup = (inter / denom) > 0.45f;            // exact ref expression
          sup = sup || s_sup;
        }
      }
      if (__ballot(sup) == 0ULL) {
        if (lane == (nk & 63)) {
          switch (nk >> 6) {
            case 0: kx1[0]=cur.x; ky1[0]=cur.y; kx2[0]=cur.z; ky2[0]=cur.w; kar[0]=area; kr[0]=r; break;
            case 1: kx1[1]=cur.x; ky1[1]=cur.y; kx2[1]=cur.z; ky2[1]=cur.w; kar[1]=area; kr[1]=r; break;
            case 2: kx1[2]=cur.x; ky1[2]=cur.y; kx2[2]=cur.z; ky2[2]=cur.w; kar[2]=area; kr[2]=r; break;
            default: kx1[3]=cur.x; ky1[3]=cur.y; kx2[3]=cur.z; ky2[3]=cur.w; kar[3]=area; kr[3]=r; break;
          }
        }
        ++nk;
        if (nk == D_N) break;
      }
      cur = nxt;
    }
  }
#pragma unroll
  for (int s = 0; s < 4; ++s) {
    int k = s * 64 + lane;
    if (k < nk) {
      int r = kr[s];
      unsigned sb = __float_as_uint(ts[r]);
      kept_key[(size_t)task * D_N + k] =
          ((unsigned long long)sb << 32) |
          (unsigned)(0xFFFFFFFFu - (unsigned)(c * K_TOP + r));
    }
  }
  if (lane == 0) kept_cnt[task] = nk;
}

// ---------------------------------------------------------------------------
// K4: merged merge+output. One block per image. Wave 0 runs the 90-way
//     sorted-list merge (score desc, flat idx asc == reference argmax order),
//     picks to LDS; then threads 0..199 emit boxes / top-2 scores / labels.
// ---------------------------------------------------------------------------
__global__ __launch_bounds__(256) void k4_merge_out(
    const unsigned long long* __restrict__ kept_key,
    const int* __restrict__ kept_cnt,
    const float* __restrict__ probs_t, const float* __restrict__ boxes,
    const int* __restrict__ topk_anchor, float* __restrict__ out)
{
  __shared__ int s_pick[D_N];
  const int b = blockIdx.x;
  if (threadIdx.x < 64) {
    int lane = threadIdx.x;
    int c0 = lane, c1 = 64 + lane;
    int base0 = b * FG_N + c0;
    int base1 = b * FG_N + c1;
    int cnt0 = (c0 < FG_N) ? kept_cnt[base0] : 0;
    int cnt1 = (c1 < FG_N) ? kept_cnt[base1] : 0;
    const unsigned long long* kk0 = kept_key + (size_t)base0 * D_N;
    const unsigned long long* kk1 = kept_key + (size_t)base1 * D_N;
    int h0 = 0, h1 = 0;
    unsigned long long cur0 = cnt0 > 0 ? kk0[0] : 0ULL;
    unsigned long long n0a  = cnt0 > 1 ? kk0[1] : 0ULL;
    unsigned long long n0b  = cnt0 > 2 ? kk0[2] : 0ULL;
    unsigned long long cur1 = cnt1 > 0 ? kk1[0] : 0ULL;
    unsigned long long n1a  = cnt1 > 1 ? kk1[1] : 0ULL;
    unsigned long long n1b  = cnt1 > 2 ? kk1[2] : 0ULL;
    for (int i = 0; i < D_N; ++i) {
      unsigned long long m = cur0 > cur1 ? cur0 : cur1;
#pragma unroll
      for (int d = 1; d < 64; d <<= 1) {
        unsigned long long o = __shfl_xor(m, d, 64);
        if (o > m) m = o;
      }
      if (m == 0ULL) {
        if (lane == 0) s_pick[i] = -1;
      } else {
        unsigned flat = 0xFFFFFFFFu - (unsigned)(m & 0xFFFFFFFFull);
        if (lane == 0) s_pick[i] = (int)flat;
        int cw = (int)(flat / K_TOP);
        if (cw == c0) {
          ++h0; cur0 = n0a; n0a = n0b;
          n0b = (h0 + 2 < cnt0) ? kk0[h0 + 2] : 0ULL;
        } else if (cw == c1) {
          ++h1; cur1 = n1a; n1a = n1b;
          n1b = (h1 + 2 < cnt1) ? kk1[h1 + 2] : 0ULL;
        }
      }
    }
  }
  __syncthreads();

  const int d = threadIdx.x;
  if (d >= D_N) return;
  const int t = b * D_N + d;
  float* ob = out + (size_t)t * 4;
  float* os = out + (size_t)B_N * D_N * 4 + (size_t)t * 2;
  float* ol = out + (size_t)B_N * D_N * 6 + (size_t)t * 2;
  int flat = s_pick[d];
  if (flat < 0) {
    ob[0] = 0.0f; ob[1] = 0.0f; ob[2] = 0.0f; ob[3] = 0.0f;
    os[0] = 0.0f; os[1] = 0.0f;
    ol[0] = 0.0f; ol[1] = 0.0f;
    return;
  }
  int c = flat / K_TOP;
  int r = flat - c * K_TOP;
  int anchor = topk_anchor[((size_t)b * FG_N + c) * K_TOP + r];
  const float* bp = boxes + ((size_t)b * A_N + anchor) * 4;
  ob[0] = bp[0]; ob[1] = bp[1]; ob[2] = bp[2]; ob[3] = bp[3];
  float v1 = -1.0f; int i1 = 0;
  float v2 = -1.0f; int i2 = 0;
  const float* pp = probs_t + (size_t)b * FG_N * A_N + anchor;
  for (int cc = 0; cc < FG_N; ++cc) {
    float p = pp[(size_t)cc * A_N];
    if (p > v1)      { v2 = v1; i2 = i1; v1 = p; i1 = cc; }
    else if (p > v2) { v2 = p; i2 = cc; }
  }
  os[0] = v1; os[1] = v2;
  ol[0] = (float)(i1 + 1); ol[1] = (float)(i2 + 1);
}

// ---------------------------------------------------------------------------
extern "C" void kernel_launch(void* const* d_in, const int* in_sizes, int n_in,
                              void* d_out, int out_size, void* d_ws, size_t ws_size,
                              hipStream_t stream)
{
  (void)in_sizes; (void)n_in; (void)out_size; (void)ws_size;
  const float* cls = (const float*)d_in[0];
  const float* reg = (const float*)d_in[1];
  const float* anc = (const float*)d_in[2];

  char* w = (char*)d_ws;
  size_t off = 0;
  auto carve = [&](size_t bytes) -> char* {
    char* p = w + off;
    off += (bytes + 255) & ~(size_t)255;
    return p;
  };
  float* probs_t                = (float*)carve((size_t)B_N * FG_N * A_N * 4);
  float* boxes                  = (float*)carve((size_t)B_N * A_N * 4 * 4);
  int* topk_anchor              = (int*)carve((size_t)NTASK * K_TOP * 4);
  float* topk_score             = (float*)carve((size_t)NTASK * K_TOP * 4);
  int* topk_cnt                 = (int*)carve((size_t)NTASK * 4);
  unsigned long long* kept_key  = (unsigned long long*)carve((size_t)NTASK * D_N * 8);
  int* kept_cnt                 = (int*)carve((size_t)NTASK * 4);

  hipLaunchKernelGGL(k1_softmax_decode, dim3((B_N * A_N + 255) / 256), dim3(256), 0, stream,
                     cls, reg, anc, probs_t, boxes);
  hipLaunchKernelGGL(k2_topk, dim3(NTASK), dim3(256), 0, stream,
                     probs_t, topk_anchor, topk_score, topk_cnt);
  hipLaunchKernelGGL(k3_nms, dim3(NTASK / 4), dim3(256), 0, stream,
                     boxes, topk_anchor, topk_score, topk_cnt, kept_key, kept_cnt);
  hipLaunchKernelGGL(k4_merge_out, dim3(B_N), dim3(256), 0, stream,
                     kept_key, kept_cnt, probs_t, boxes, topk_anchor, (float*)d_out);
}

// Round 5
// 516.429 us; speedup vs baseline: 1.3551x; 1.0716x over previous
//
#include <hip/hip_runtime.h>
#include <cstdint>
#include <cstddef>

#define B_N   16
#define A_N   8732
#define C_N   91
#define FG_N  90
#define K_TOP 400
#define D_N   200
#define NTASK (B_N * FG_N)   // 1440

// ---------------------------------------------------------------------------
// K1: per-anchor softmax (store fg probs transposed (B, 90, A)) + box decode
// ---------------------------------------------------------------------------
__global__ __launch_bounds__(256) void k1_softmax_decode(
    const float* __restrict__ cls, const float* __restrict__ reg,
    const float* __restrict__ anc, float* __restrict__ probs_t,
    float* __restrict__ boxes)
{
#pragma clang fp contract(off)
  int t = blockIdx.x * 256 + threadIdx.x;
  if (t >= B_N * A_N) return;
  int b = t / A_N;
  int a = t - b * A_N;
  const float* lg = cls + (size_t)t * C_N;
  float m = lg[0];
  for (int c = 1; c < C_N; ++c) m = fmaxf(m, lg[c]);
  float s = 0.0f;
  for (int c = 0; c < C_N; ++c) s += expf(lg[c] - m);
  for (int c = 1; c < C_N; ++c)
    probs_t[((size_t)b * FG_N + (c - 1)) * A_N + a] = expf(lg[c] - m) / s;

  float4 rl = *(const float4*)(reg + (size_t)t * 4);
  float4 an = *(const float4*)(anc + (size_t)a * 4);
  float wa = an.z - an.x;
  float ha = an.w - an.y;
  float cxa = an.x + 0.5f * wa;
  float cya = an.y + 0.5f * ha;
  float dx = rl.x / 10.0f;
  float dy = rl.y / 10.0f;
  const float clipv = 4.135166556742356f;   // log(1000/16)
  float dw = fminf(rl.z / 5.0f, clipv);
  float dh = fminf(rl.w / 5.0f, clipv);
  float t1 = dx * wa;  float cx = t1 + cxa;
  float t2 = dy * ha;  float cy = t2 + cya;
  float w = expf(dw) * wa;
  float h = expf(dh) * ha;
  float4 out;
  out.x = fminf(fmaxf(cx - 0.5f * w, 0.0f), 300.0f);
  out.y = fminf(fmaxf(cy - 0.5f * h, 0.0f), 300.0f);
  out.z = fminf(fmaxf(cx + 0.5f * w, 0.0f), 300.0f);
  out.w = fminf(fmaxf(cy + 0.5f * h, 0.0f), 300.0f);
  *(float4*)(boxes + (size_t)t * 4) = out;
}

// ---------------------------------------------------------------------------
// K2: exact top-400 per (image, fg-class). Common path: single global pass
//     collects all >0.01 candidates (~900 avg) straight into the 1024-slot
//     LDS buffer, then bitonic sort. Radix-select fallback (with a second
//     global pass) runs only when count > 1024 — exact, rarely taken.
// ---------------------------------------------------------------------------
__device__ __forceinline__ void scan_select(int* hist, int nbins, int need,
                                            int tid, int* chunk, int* res)
{
  int per = nbins >> 8;            // 4096 -> 16, 256 -> 1
  int s = 0;
  for (int i = 0; i < per; ++i) s += hist[tid * per + i];
  chunk[tid] = s;
  __syncthreads();
  if (tid == 0) {
    int cum = 0;
    for (int t2 = 255; t2 >= 0; --t2) { int v = chunk[t2]; chunk[t2] = cum; cum += v; }
  }
  __syncthreads();
  int cum = chunk[tid];            // count in strictly-higher chunks
  for (int i = per - 1; i >= 0; --i) {
    int bn = tid * per + i;
    int h = hist[bn];
    if (cum < need && need <= cum + h) { res[0] = bn; res[1] = cum; }
    cum += h;
  }
  __syncthreads();
}

__global__ __launch_bounds__(256) void k2_topk(
    const float* __restrict__ probs_t, int* __restrict__ topk_anchor,
    float* __restrict__ topk_score, int* __restrict__ topk_cnt)
{
  __shared__ int hist[4096];
  __shared__ int chunk[256];
  __shared__ int res[2];
  __shared__ int s_lcnt;
  __shared__ unsigned long long lst[1024];
  const int task = blockIdx.x;
  const int tid = threadIdx.x;
  const float* sc = probs_t + (size_t)task * A_N;

  if (tid == 0) s_lcnt = 0;
  __syncthreads();
  // Pass 1: collect every candidate >0.01 (count is exact; stores capped)
  for (int a = tid; a < A_N; a += 256) {
    float p = sc[a];
    if (p > 0.01f) {
      unsigned k = __float_as_uint(p);
      int pos = atomicAdd(&s_lcnt, 1);
      if (pos < 1024)
        lst[pos] = ((unsigned long long)k << 32) | (unsigned)(0xFFFFFFFFu - (unsigned)a);
    }
  }
  __syncthreads();
  const int total = s_lcnt;
  const int ksel = total < K_TOP ? total : K_TOP;
  int n;
  if (total <= 1024) {
    n = total;                       // common path: everything already in lst
    __syncthreads();
  } else {
    // Fallback: radix select on float bits over a second global pass.
    for (int i = tid; i < 4096; i += 256) hist[i] = 0;
    __syncthreads();
    for (int a = tid; a < A_N; a += 256) {
      float p = sc[a];
      if (p > 0.01f) atomicAdd(&hist[__float_as_uint(p) >> 20], 1);
    }
    __syncthreads();
    int need = K_TOP;
    scan_select(hist, 4096, need, tid, chunk, res);
    const unsigned b1 = (unsigned)res[0];
    const int above1 = res[1];
    const int in1 = hist[b1];
    __syncthreads();
    unsigned cutoff;
    if (above1 + in1 <= 1024) {
      cutoff = b1 << 20;             // coarse cutoff fits buffer: done
    } else {
      need -= above1;
      for (int i = tid; i < 4096; i += 256) hist[i] = 0;
      __syncthreads();
      for (int a = tid; a < A_N; a += 256) {
        float p = sc[a];
        if (p > 0.01f) {
          unsigned k = __float_as_uint(p);
          if ((k >> 20) == b1) atomicAdd(&hist[(k >> 8) & 0xFFFu], 1);
        }
      }
      __syncthreads();
      scan_select(hist, 4096, need, tid, chunk, res);
      const unsigned b2 = (unsigned)res[0];
      need -= res[1];
      const unsigned pre12 = (b1 << 12) | b2;   // value of (key >> 8)
      __syncthreads();
      hist[tid] = 0;
      __syncthreads();
      for (int a = tid; a < A_N; a += 256) {
        float p = sc[a];
        if (p > 0.01f) {
          unsigned k = __float_as_uint(p);
          if ((k >> 8) == pre12) atomicAdd(&hist[k & 0xFFu], 1);
        }
      }
      __syncthreads();
      scan_select(hist, 256, need, tid, chunk, res);
      cutoff = (pre12 << 8) | (unsigned)res[0];
      __syncthreads();
    }
    if (tid == 0) s_lcnt = 0;
    __syncthreads();
    for (int a = tid; a < A_N; a += 256) {
      float p = sc[a];
      if (p > 0.01f) {
        unsigned k = __float_as_uint(p);
        if (k >= cutoff) {
          int pos = atomicAdd(&s_lcnt, 1);
          if (pos < 1024)
            lst[pos] = ((unsigned long long)k << 32) | (unsigned)(0xFFFFFFFFu - (unsigned)a);
        }
      }
    }
    __syncthreads();
    n = s_lcnt < 1024 ? s_lcnt : 1024;
  }

  const int W = (n <= 512) ? 512 : 1024;
  for (int i = tid; i < W; i += 256) if (i >= n) lst[i] = 0ULL;
  __syncthreads();
  // bitonic sort, descending; (score desc, anchor asc) via ~anchor in low bits
  for (int kk = 2; kk <= W; kk <<= 1) {
    for (int jj = kk >> 1; jj > 0; jj >>= 1) {
      for (int i = tid; i < W; i += 256) {
        int ix = i ^ jj;
        if (ix > i) {
          unsigned long long va = lst[i], vb = lst[ix];
          bool desc = ((i & kk) == 0);
          if (desc ? (va < vb) : (va > vb)) { lst[i] = vb; lst[ix] = va; }
        }
      }
      __syncthreads();
    }
  }
  for (int r = tid; r < K_TOP; r += 256) {
    int anchor = 0;
    float scv = -1.0f;
    if (r < ksel) {
      unsigned long long v = lst[r];
      anchor = (int)(0xFFFFFFFFu - (unsigned)(v & 0xFFFFFFFFull));
      scv = __uint_as_float((unsigned)(v >> 32));
    }
    topk_anchor[(size_t)task * K_TOP + r] = anchor;
    topk_score[(size_t)task * K_TOP + r] = scv;
  }
  if (tid == 0) topk_cnt[task] = ksel;
}

// ---------------------------------------------------------------------------
// K3: chunked greedy NMS, one wave per (image,class). Candidates processed in
//     score-ordered chunks of 64 (lane = candidate). Per chunk: parallel test
//     vs kept list (LDS broadcast, no loop-carried chain), then intra-chunk
//     resolve visiting only survivors (ffs over todo mask + shuffle broadcast
//     + ballot), then parallel rank-and-append (order = score order). Greedy
//     result is identical to the serial scan; IoU decisions bit-match the
//     reference (same op order, division-free compare with exact-div fallback
//     band). Kept capped at 200 = first 200 survivors.
// ---------------------------------------------------------------------------
__global__ __launch_bounds__(256) void k3_nms(
    const float* __restrict__ boxes, const int* __restrict__ topk_anchor,
    const float* __restrict__ topk_score, const int* __restrict__ topk_cnt,
    unsigned long long* __restrict__ kept_key, int* __restrict__ kept_cnt)
{
#pragma clang fp contract(off)
  __shared__ float4 keptb[4][D_N];   // 12.8 KB
  __shared__ float  kepta[4][D_N];   //  3.2 KB
  __shared__ int    keptr[4][D_N];   //  3.2 KB
  const int wid  = threadIdx.x >> 6;
  const int lane = threadIdx.x & 63;
  const int task = blockIdx.x * 4 + wid;   // grid is exactly NTASK/4
  const int b = task / FG_N;
  const int c = task - b * FG_N;
  const float off = (float)(c + 1) * 302.0f;
  const int cnt = topk_cnt[task];
  const int* ta = topk_anchor + (size_t)task * K_TOP;
  const float* ts = topk_score + (size_t)task * K_TOP;
  const float* bx = boxes + (size_t)b * (A_N * 4);

  int nk = 0;
  // prefetch chunk 0
  float4 nxt = make_float4(0.0f, 0.0f, 0.0f, 0.0f);
  if (lane < cnt) {
    int a0 = ta[lane];
    nxt = *(const float4*)(bx + (size_t)a0 * 4);
  }
  for (int c0 = 0; c0 < cnt && nk < D_N; c0 += 64) {
    float4 cur = nxt;
    // prefetch next chunk (issued before the kept-test loop to hide latency)
    int nidx = c0 + 64 + lane;
    if (nidx < cnt) {
      int an = ta[nidx];
      nxt = *(const float4*)(bx + (size_t)an * 4);
    }
    const bool validc = (c0 + lane) < cnt;
    cur.x += off; cur.y += off; cur.z += off; cur.w += off;
    const float area = (cur.z - cur.x) * (cur.w - cur.y);

    // (a) parallel: suppressed-by-kept test, independent iterations
    bool sup = !validc;
    for (int k = 0; k < nk; ++k) {
      float4 kb = keptb[wid][k];           // broadcast read, conflict-free
      float  ka = kepta[wid][k];
      float ix1 = fmaxf(cur.x, kb.x);
      float iy1 = fmaxf(cur.y, kb.y);
      float ix2 = fminf(cur.z, kb.z);
      float iy2 = fminf(cur.w, kb.w);
      float inter = fmaxf(ix2 - ix1, 0.0f) * fmaxf(iy2 - iy1, 0.0f);
      float denom = ka + area - inter + 1e-9f;
      float thr = 0.45f * denom;
      bool s_sup = inter > thr;
      if (fabsf(inter - thr) <= 1.5e-6f * thr)   // ambiguous band: rare
        s_sup = (inter / denom) > 0.45f;         // exact ref expression
      sup = sup || s_sup;
    }

    // (b) intra-chunk resolve: visit survivors in order, suppress forward
    unsigned long long todo = ~__ballot(sup);
    unsigned long long surv = 0ULL;
    int ns = 0;
    const int room = D_N - nk;
    while (todo) {
      if (ns == room) break;                 // greedy stops at 200 keeps
      int j = __ffsll((unsigned long long)todo) - 1;
      surv |= 1ULL << j;
      ++ns;
      todo &= ~(1ULL << j);
      float jx1 = __shfl(cur.x, j);
      float jy1 = __shfl(cur.y, j);
      float jx2 = __shfl(cur.z, j);
      float jy2 = __shfl(cur.w, j);
      float ja  = __shfl(area, j);
      float ix1 = fmaxf(jx1, cur.x);
      float iy1 = fmaxf(jy1, cur.y);
      float ix2 = fminf(jx2, cur.z);
      float iy2 = fminf(jy2, cur.w);
      float inter = fmaxf(ix2 - ix1, 0.0f) * fmaxf(iy2 - iy1, 0.0f);
      float denom = ja + area - inter + 1e-9f;
      float thr = 0.45f * denom;
      bool s_sup = inter > thr;
      if (fabsf(inter - thr) <= 1.5e-6f * thr)
        s_sup = (inter / denom) > 0.45f;
      unsigned long long supj = __ballot(s_sup);
      supj &= ~(1ULL << j);                  // self-IoU = 1, mask out
      todo &= ~supj;
    }

    // (c) parallel append, order = lane order = score order
    if ((surv >> lane) & 1ULL) {
      int my = nk + __popcll(surv & ((1ULL << lane) - 1ULL));
      keptb[wid][my] = cur;
      kepta[wid][my] = area;
      keptr[wid][my] = c0 + lane;
    }
    nk += ns;
  }

  for (int k = lane; k < nk; k += 64) {
    int r = keptr[wid][k];
    unsigned sb = __float_as_uint(ts[r]);
    kept_key[(size_t)task * D_N + k] =
        ((unsigned long long)sb << 32) |
        (unsigned)(0xFFFFFFFFu - (unsigned)(c * K_TOP + r));
  }
  if (lane == 0) kept_cnt[task] = nk;
}

// ---------------------------------------------------------------------------
// K4: merged merge+output. One block per image. Wave 0 runs the 90-way
//     sorted-list merge (score desc, flat idx asc == reference argmax order),
//     picks to LDS; then threads 0..199 emit boxes / top-2 scores / labels.
// ---------------------------------------------------------------------------
__global__ __launch_bounds__(256) void k4_merge_out(
    const unsigned long long* __restrict__ kept_key,
    const int* __restrict__ kept_cnt,
    const float* __restrict__ probs_t, const float* __restrict__ boxes,
    const int* __restrict__ topk_anchor, float* __restrict__ out)
{
  __shared__ int s_pick[D_N];
  const int b = blockIdx.x;
  if (threadIdx.x < 64) {
    int lane = threadIdx.x;
    int c0 = lane, c1 = 64 + lane;
    int base0 = b * FG_N + c0;
    int base1 = b * FG_N + c1;
    int cnt0 = (c0 < FG_N) ? kept_cnt[base0] : 0;
    int cnt1 = (c1 < FG_N) ? kept_cnt[base1] : 0;
    const unsigned long long* kk0 = kept_key + (size_t)base0 * D_N;
    const unsigned long long* kk1 = kept_key + (size_t)base1 * D_N;
    int h0 = 0, h1 = 0;
    unsigned long long cur0 = cnt0 > 0 ? kk0[0] : 0ULL;
    unsigned long long n0a  = cnt0 > 1 ? kk0[1] : 0ULL;
    unsigned long long n0b  = cnt0 > 2 ? kk0[2] : 0ULL;
    unsigned long long cur1 = cnt1 > 0 ? kk1[0] : 0ULL;
    unsigned long long n1a  = cnt1 > 1 ? kk1[1] : 0ULL;
    unsigned long long n1b  = cnt1 > 2 ? kk1[2] : 0ULL;
    for (int i = 0; i < D_N; ++i) {
      unsigned long long m = cur0 > cur1 ? cur0 : cur1;
#pragma unroll
      for (int d = 1; d < 64; d <<= 1) {
        unsigned long long o = __shfl_xor(m, d, 64);
        if (o > m) m = o;
      }
      if (m == 0ULL) {
        if (lane == 0) s_pick[i] = -1;
      } else {
        unsigned flat = 0xFFFFFFFFu - (unsigned)(m & 0xFFFFFFFFull);
        if (lane == 0) s_pick[i] = (int)flat;
        int cw = (int)(flat / K_TOP);
        if (cw == c0) {
          ++h0; cur0 = n0a; n0a = n0b;
          n0b = (h0 + 2 < cnt0) ? kk0[h0 + 2] : 0ULL;
        } else if (cw == c1) {
          ++h1; cur1 = n1a; n1a = n1b;
          n1b = (h1 + 2 < cnt1) ? kk1[h1 + 2] : 0ULL;
        }
      }
    }
  }
  __syncthreads();

  const int d = threadIdx.x;
  if (d >= D_N) return;
  const int t = b * D_N + d;
  float* ob = out + (size_t)t * 4;
  float* os = out + (size_t)B_N * D_N * 4 + (size_t)t * 2;
  float* ol = out + (size_t)B_N * D_N * 6 + (size_t)t * 2;
  int flat = s_pick[d];
  if (flat < 0) {
    ob[0] = 0.0f; ob[1] = 0.0f; ob[2] = 0.0f; ob[3] = 0.0f;
    os[0] = 0.0f; os[1] = 0.0f;
    ol[0] = 0.0f; ol[1] = 0.0f;
    return;
  }
  int c = flat / K_TOP;
  int r = flat - c * K_TOP;
  int anchor = topk_anchor[((size_t)b * FG_N + c) * K_TOP + r];
  const float* bp = boxes + ((size_t)b * A_N + anchor) * 4;
  ob[0] = bp[0]; ob[1] = bp[1]; ob[2] = bp[2]; ob[3] = bp[3];
  float v1 = -1.0f; int i1 = 0;
  float v2 = -1.0f; int i2 = 0;
  const float* pp = probs_t + (size_t)b * FG_N * A_N + anchor;
  for (int cc = 0; cc < FG_N; ++cc) {
    float p = pp[(size_t)cc * A_N];
    if (p > v1)      { v2 = v1; i2 = i1; v1 = p; i1 = cc; }
    else if (p > v2) { v2 = p; i2 = cc; }
  }
  os[0] = v1; os[1] = v2;
  ol[0] = (float)(i1 + 1); ol[1] = (float)(i2 + 1);
}

// ---------------------------------------------------------------------------
extern "C" void kernel_launch(void* const* d_in, const int* in_sizes, int n_in,
                              void* d_out, int out_size, void* d_ws, size_t ws_size,
                              hipStream_t stream)
{
  (void)in_sizes; (void)n_in; (void)out_size; (void)ws_size;
  const float* cls = (const float*)d_in[0];
  const float* reg = (const float*)d_in[1];
  const float* anc = (const float*)d_in[2];

  char* w = (char*)d_ws;
  size_t off = 0;
  auto carve = [&](size_t bytes) -> char* {
    char* p = w + off;
    off += (bytes + 255) & ~(size_t)255;
    return p;
  };
  float* probs_t                = (float*)carve((size_t)B_N * FG_N * A_N * 4);
  float* boxes                  = (float*)carve((size_t)B_N * A_N * 4 * 4);
  int* topk_anchor              = (int*)carve((size_t)NTASK * K_TOP * 4);
  float* topk_score             = (float*)carve((size_t)NTASK * K_TOP * 4);
  int* topk_cnt                 = (int*)carve((size_t)NTASK * 4);
  unsigned long long* kept_key  = (unsigned long long*)carve((size_t)NTASK * D_N * 8);
  int* kept_cnt                 = (int*)carve((size_t)NTASK * 4);

  hipLaunchKernelGGL(k1_softmax_decode, dim3((B_N * A_N + 255) / 256), dim3(256), 0, stream,
                     cls, reg, anc, probs_t, boxes);
  hipLaunchKernelGGL(k2_topk, dim3(NTASK), dim3(256), 0, stream,
                     probs_t, topk_anchor, topk_score, topk_cnt);
  hipLaunchKernelGGL(k3_nms, dim3(NTASK / 4), dim3(256), 0, stream,
                     boxes, topk_anchor, topk_score, topk_cnt, kept_key, kept_cnt);
  hipLaunchKernelGGL(k4_merge_out, dim3(B_N), dim3(256), 0, stream,
                     kept_key, kept_cnt, probs_t, boxes, topk_anchor, (float*)d_out);
}

// Round 6
// 405.822 us; speedup vs baseline: 1.7244x; 1.2725x over previous
//
#include <hip/hip_runtime.h>
#include <cstdint>
#include <cstddef>

#define B_N   16
#define A_N   8732
#define C_N   91
#define FG_N  90
#define K_TOP 400
#define D_N   200
#define NTASK (B_N * FG_N)   // 1440
#define K1_APB 128           // anchors per block in k1
#define K1_NBLK ((A_N + K1_APB - 1) / K1_APB)   // 69

// ---------------------------------------------------------------------------
// K1: softmax + decode, LDS-staged. Block = 128 threads = 128 anchors of one
//     image. Loads the 128x91 logit slab coalesced (float4), computes from
//     LDS (stride-91 = odd = conflict-free), stores exp back to LDS so expf
//     runs once per element. Exact reference op order: sequential max over
//     c=0..90, sequential sum, exact e/s division. Transposed prob store
//     (B,90,A) stays coalesced (thread=anchor contiguous).
// ---------------------------------------------------------------------------
__global__ __launch_bounds__(128) void k1_softmax_decode(
    const float* __restrict__ cls, const float* __restrict__ reg,
    const float* __restrict__ anc, float* __restrict__ probs_t,
    float* __restrict__ boxes)
{
#pragma clang fp contract(off)
  __shared__ float4 lds4[(K1_APB * C_N + 3) / 4];   // 46.6 KB
  float* lds = (float*)lds4;
  const int bb = blockIdx.x;
  const int b = bb / K1_NBLK;
  const int blk = bb - b * K1_NBLK;
  const int a0 = blk * K1_APB;
  const int nloc = (A_N - a0) < K1_APB ? (A_N - a0) : K1_APB;
  const int tid = threadIdx.x;

  // coalesced stage: base element is divisible by 4 (91*128 and 91*8732 are)
  const size_t gbase_f4 = ((size_t)(b * A_N + a0) * C_N) >> 2;
  const size_t TOT_F4 = ((size_t)B_N * A_N * C_N) >> 2;
  const float4* cls4 = (const float4*)cls;
  constexpr int NF4 = (K1_APB * C_N) / 4;           // 2912
  for (int i = tid; i < NF4; i += K1_APB) {
    size_t g = gbase_f4 + i;
    if (g < TOT_F4) lds4[i] = cls4[g];
  }
  __syncthreads();

  if (tid >= nloc) return;
  const int a = a0 + tid;
  const int tg = b * A_N + a;
  float* lg = lds + tid * C_N;

  float m = lg[0];
  for (int c = 1; c < C_N; ++c) m = fmaxf(m, lg[c]);
  float s = 0.0f;
  for (int c = 0; c < C_N; ++c) {
    float e = expf(lg[c] - m);
    s += e;
    lg[c] = e;                       // overwrite: exp computed once
  }
  for (int c = 1; c < C_N; ++c)
    probs_t[((size_t)b * FG_N + (c - 1)) * A_N + a] = lg[c] / s;

  float4 rl = *(const float4*)(reg + (size_t)tg * 4);
  float4 an = *(const float4*)(anc + (size_t)a * 4);
  float wa = an.z - an.x;
  float ha = an.w - an.y;
  float cxa = an.x + 0.5f * wa;
  float cya = an.y + 0.5f * ha;
  float dx = rl.x / 10.0f;
  float dy = rl.y / 10.0f;
  const float clipv = 4.135166556742356f;   // log(1000/16)
  float dw = fminf(rl.z / 5.0f, clipv);
  float dh = fminf(rl.w / 5.0f, clipv);
  float t1 = dx * wa;  float cx = t1 + cxa;
  float t2 = dy * ha;  float cy = t2 + cya;
  float w = expf(dw) * wa;
  float h = expf(dh) * ha;
  float4 out;
  out.x = fminf(fmaxf(cx - 0.5f * w, 0.0f), 300.0f);
  out.y = fminf(fmaxf(cy - 0.5f * h, 0.0f), 300.0f);
  out.z = fminf(fmaxf(cx + 0.5f * w, 0.0f), 300.0f);
  out.w = fminf(fmaxf(cy + 0.5f * h, 0.0f), 300.0f);
  *(float4*)(boxes + (size_t)tg * 4) = out;
}

// ---------------------------------------------------------------------------
// shared helper: descending rank-select over a 256-chunked histogram
// ---------------------------------------------------------------------------
__device__ __forceinline__ void scan_select(int* hist, int nbins, int need,
                                            int tid, int* chunk, int* res)
{
  int per = nbins >> 8;            // 4096 -> 16, 256 -> 1
  int s = 0;
  for (int i = 0; i < per; ++i) s += hist[tid * per + i];
  chunk[tid] = s;
  __syncthreads();
  if (tid == 0) {
    int cum = 0;
    for (int t2 = 255; t2 >= 0; --t2) { int v = chunk[t2]; chunk[t2] = cum; cum += v; }
  }
  __syncthreads();
  int cum = chunk[tid];            // count in strictly-higher chunks
  for (int i = per - 1; i >= 0; --i) {
    int bn = tid * per + i;
    int h = hist[bn];
    if (cum < need && need <= cum + h) { res[0] = bn; res[1] = cum; }
    cum += h;
  }
  __syncthreads();
}

// ---------------------------------------------------------------------------
// K2: exact top-400 per (image, fg-class). Common path: single global pass
//     collects all >0.01 candidates (~900 avg) straight into the 1024-slot
//     LDS buffer, then bitonic sort. Radix-select fallback (second global
//     pass) only when count > 1024 — exact, rarely taken.
// ---------------------------------------------------------------------------
__global__ __launch_bounds__(256) void k2_topk(
    const float* __restrict__ probs_t, int* __restrict__ topk_anchor,
    float* __restrict__ topk_score, int* __restrict__ topk_cnt)
{
  __shared__ int hist[4096];
  __shared__ int chunk[256];
  __shared__ int res[2];
  __shared__ int s_lcnt;
  __shared__ unsigned long long lst[1024];
  const int task = blockIdx.x;
  const int tid = threadIdx.x;
  const float* sc = probs_t + (size_t)task * A_N;

  if (tid == 0) s_lcnt = 0;
  __syncthreads();
  for (int a = tid; a < A_N; a += 256) {
    float p = sc[a];
    if (p > 0.01f) {
      unsigned k = __float_as_uint(p);
      int pos = atomicAdd(&s_lcnt, 1);
      if (pos < 1024)
        lst[pos] = ((unsigned long long)k << 32) | (unsigned)(0xFFFFFFFFu - (unsigned)a);
    }
  }
  __syncthreads();
  const int total = s_lcnt;
  const int ksel = total < K_TOP ? total : K_TOP;
  int n;
  if (total <= 1024) {
    n = total;
    __syncthreads();
  } else {
    for (int i = tid; i < 4096; i += 256) hist[i] = 0;
    __syncthreads();
    for (int a = tid; a < A_N; a += 256) {
      float p = sc[a];
      if (p > 0.01f) atomicAdd(&hist[__float_as_uint(p) >> 20], 1);
    }
    __syncthreads();
    int need = K_TOP;
    scan_select(hist, 4096, need, tid, chunk, res);
    const unsigned b1 = (unsigned)res[0];
    const int above1 = res[1];
    const int in1 = hist[b1];
    __syncthreads();
    unsigned cutoff;
    if (above1 + in1 <= 1024) {
      cutoff = b1 << 20;
    } else {
      need -= above1;
      for (int i = tid; i < 4096; i += 256) hist[i] = 0;
      __syncthreads();
      for (int a = tid; a < A_N; a += 256) {
        float p = sc[a];
        if (p > 0.01f) {
          unsigned k = __float_as_uint(p);
          if ((k >> 20) == b1) atomicAdd(&hist[(k >> 8) & 0xFFFu], 1);
        }
      }
      __syncthreads();
      scan_select(hist, 4096, need, tid, chunk, res);
      const unsigned b2 = (unsigned)res[0];
      need -= res[1];
      const unsigned pre12 = (b1 << 12) | b2;
      __syncthreads();
      hist[tid] = 0;
      __syncthreads();
      for (int a = tid; a < A_N; a += 256) {
        float p = sc[a];
        if (p > 0.01f) {
          unsigned k = __float_as_uint(p);
          if ((k >> 8) == pre12) atomicAdd(&hist[k & 0xFFu], 1);
        }
      }
      __syncthreads();
      scan_select(hist, 256, need, tid, chunk, res);
      cutoff = (pre12 << 8) | (unsigned)res[0];
      __syncthreads();
    }
    if (tid == 0) s_lcnt = 0;
    __syncthreads();
    for (int a = tid; a < A_N; a += 256) {
      float p = sc[a];
      if (p > 0.01f) {
        unsigned k = __float_as_uint(p);
        if (k >= cutoff) {
          int pos = atomicAdd(&s_lcnt, 1);
          if (pos < 1024)
            lst[pos] = ((unsigned long long)k << 32) | (unsigned)(0xFFFFFFFFu - (unsigned)a);
        }
      }
    }
    __syncthreads();
    n = s_lcnt < 1024 ? s_lcnt : 1024;
  }

  const int W = (n <= 512) ? 512 : 1024;
  for (int i = tid; i < W; i += 256) if (i >= n) lst[i] = 0ULL;
  __syncthreads();
  for (int kk = 2; kk <= W; kk <<= 1) {
    for (int jj = kk >> 1; jj > 0; jj >>= 1) {
      for (int i = tid; i < W; i += 256) {
        int ix = i ^ jj;
        if (ix > i) {
          unsigned long long va = lst[i], vb = lst[ix];
          bool desc = ((i & kk) == 0);
          if (desc ? (va < vb) : (va > vb)) { lst[i] = vb; lst[ix] = va; }
        }
      }
      __syncthreads();
    }
  }
  for (int r = tid; r < K_TOP; r += 256) {
    int anchor = 0;
    float scv = -1.0f;
    if (r < ksel) {
      unsigned long long v = lst[r];
      anchor = (int)(0xFFFFFFFFu - (unsigned)(v & 0xFFFFFFFFull));
      scv = __uint_as_float((unsigned)(v >> 32));
    }
    topk_anchor[(size_t)task * K_TOP + r] = anchor;
    topk_score[(size_t)task * K_TOP + r] = scv;
  }
  if (tid == 0) topk_cnt[task] = ksel;
}

// ---------------------------------------------------------------------------
// K3: chunked greedy NMS, one wave per (image,class) — identical result to
//     the serial scan; IoU decisions bit-match the reference.
// ---------------------------------------------------------------------------
__global__ __launch_bounds__(256) void k3_nms(
    const float* __restrict__ boxes, const int* __restrict__ topk_anchor,
    const float* __restrict__ topk_score, const int* __restrict__ topk_cnt,
    unsigned long long* __restrict__ kept_key, int* __restrict__ kept_cnt)
{
#pragma clang fp contract(off)
  __shared__ float4 keptb[4][D_N];
  __shared__ float  kepta[4][D_N];
  __shared__ int    keptr[4][D_N];
  const int wid  = threadIdx.x >> 6;
  const int lane = threadIdx.x & 63;
  const int task = blockIdx.x * 4 + wid;
  const int b = task / FG_N;
  const int c = task - b * FG_N;
  const float off = (float)(c + 1) * 302.0f;
  const int cnt = topk_cnt[task];
  const int* ta = topk_anchor + (size_t)task * K_TOP;
  const float* ts = topk_score + (size_t)task * K_TOP;
  const float* bx = boxes + (size_t)b * (A_N * 4);

  int nk = 0;
  float4 nxt = make_float4(0.0f, 0.0f, 0.0f, 0.0f);
  if (lane < cnt) {
    int a0 = ta[lane];
    nxt = *(const float4*)(bx + (size_t)a0 * 4);
  }
  for (int c0 = 0; c0 < cnt && nk < D_N; c0 += 64) {
    float4 cur = nxt;
    int nidx = c0 + 64 + lane;
    if (nidx < cnt) {
      int an = ta[nidx];
      nxt = *(const float4*)(bx + (size_t)an * 4);
    }
    const bool validc = (c0 + lane) < cnt;
    cur.x += off; cur.y += off; cur.z += off; cur.w += off;
    const float area = (cur.z - cur.x) * (cur.w - cur.y);

    bool sup = !validc;
    for (int k = 0; k < nk; ++k) {
      float4 kb = keptb[wid][k];
      float  ka = kepta[wid][k];
      float ix1 = fmaxf(cur.x, kb.x);
      float iy1 = fmaxf(cur.y, kb.y);
      float ix2 = fminf(cur.z, kb.z);
      float iy2 = fminf(cur.w, kb.w);
      float inter = fmaxf(ix2 - ix1, 0.0f) * fmaxf(iy2 - iy1, 0.0f);
      float denom = ka + area - inter + 1e-9f;
      float thr = 0.45f * denom;
      bool s_sup = inter > thr;
      if (fabsf(inter - thr) <= 1.5e-6f * thr)
        s_sup = (inter / denom) > 0.45f;
      sup = sup || s_sup;
    }

    unsigned long long todo = ~__ballot(sup);
    unsigned long long surv = 0ULL;
    int ns = 0;
    const int room = D_N - nk;
    while (todo) {
      if (ns == room) break;
      int j = __ffsll((unsigned long long)todo) - 1;
      surv |= 1ULL << j;
      ++ns;
      todo &= ~(1ULL << j);
      float jx1 = __shfl(cur.x, j);
      float jy1 = __shfl(cur.y, j);
      float jx2 = __shfl(cur.z, j);
      float jy2 = __shfl(cur.w, j);
      float ja  = __shfl(area, j);
      float ix1 = fmaxf(jx1, cur.x);
      float iy1 = fmaxf(jy1, cur.y);
      float ix2 = fminf(jx2, cur.z);
      float iy2 = fminf(jy2, cur.w);
      float inter = fmaxf(ix2 - ix1, 0.0f) * fmaxf(iy2 - iy1, 0.0f);
      float denom = ja + area - inter + 1e-9f;
      float thr = 0.45f * denom;
      bool s_sup = inter > thr;
      if (fabsf(inter - thr) <= 1.5e-6f * thr)
        s_sup = (inter / denom) > 0.45f;
      unsigned long long supj = __ballot(s_sup);
      supj &= ~(1ULL << j);
      todo &= ~supj;
    }

    if ((surv >> lane) & 1ULL) {
      int my = nk + __popcll(surv & ((1ULL << lane) - 1ULL));
      keptb[wid][my] = cur;
      kepta[wid][my] = area;
      keptr[wid][my] = c0 + lane;
    }
    nk += ns;
  }

  for (int k = lane; k < nk; k += 64) {
    int r = keptr[wid][k];
    unsigned sb = __float_as_uint(ts[r]);
    kept_key[(size_t)task * D_N + k] =
        ((unsigned long long)sb << 32) |
        (unsigned)(0xFFFFFFFFu - (unsigned)(c * K_TOP + r));
  }
  if (lane == 0) kept_cnt[task] = nk;
}

// ---------------------------------------------------------------------------
// K4: per-image global pick selection. The 200 greedy picks are exactly the
//     top-200 survivor keys (suppression already applied per class; picks
//     don't interact) — so this is a parallel radix-select + bitonic sort
//     over <=18000 survivor keys, not a serial merge. One block per image.
// ---------------------------------------------------------------------------
__global__ __launch_bounds__(256) void k4_sel(
    const unsigned long long* __restrict__ kept_key,
    const int* __restrict__ kept_cnt, int* __restrict__ pick_flat)
{
  __shared__ int hist[4096];
  __shared__ int chunk[256];
  __shared__ int res[2];
  __shared__ int s_lcnt;
  __shared__ int s_cnts[FG_N];
  __shared__ unsigned long long lst[1024];
  const int b = blockIdx.x;
  const int tid = threadIdx.x;
  const unsigned long long* kb = kept_key + (size_t)b * FG_N * D_N;

  if (tid < FG_N) s_cnts[tid] = kept_cnt[b * FG_N + tid];
  for (int i = tid; i < 4096; i += 256) hist[i] = 0;
  if (tid == 0) s_lcnt = 0;
  __syncthreads();

  // histogram over top-12 score bits (= key >> 52); also count total
  for (int idx = tid; idx < FG_N * D_N; idx += 256) {
    int c = idx / D_N, r = idx - c * D_N;
    if (r < s_cnts[c]) {
      unsigned long long k = kb[idx];
      atomicAdd(&hist[(int)(k >> 52)], 1);
      atomicAdd(&s_lcnt, 1);
    }
  }
  __syncthreads();
  const int total = s_lcnt;
  const int npick = total < D_N ? total : D_N;
  unsigned cutoff32 = 1u;                    // all keys have positive score bits
  if (total > D_N) {
    int need = D_N;
    scan_select(hist, 4096, need, tid, chunk, res);
    const unsigned b1 = (unsigned)res[0];
    const int above1 = res[1];
    const int in1 = hist[b1];
    __syncthreads();
    if (above1 + in1 <= 1024) {
      cutoff32 = b1 << 20;
    } else {
      need -= above1;
      for (int i = tid; i < 4096; i += 256) hist[i] = 0;
      __syncthreads();
      for (int idx = tid; idx < FG_N * D_N; idx += 256) {
        int c = idx / D_N, r = idx - c * D_N;
        if (r < s_cnts[c]) {
          unsigned long long k = kb[idx];
          if ((unsigned)(k >> 52) == b1)
            atomicAdd(&hist[(int)((k >> 40) & 0xFFFull)], 1);
        }
      }
      __syncthreads();
      scan_select(hist, 4096, need, tid, chunk, res);
      const unsigned b2 = (unsigned)res[0];
      need -= res[1];
      const unsigned pre12 = (b1 << 12) | b2;
      __syncthreads();
      hist[tid] = 0;
      __syncthreads();
      for (int idx = tid; idx < FG_N * D_N; idx += 256) {
        int c = idx / D_N, r = idx - c * D_N;
        if (r < s_cnts[c]) {
          unsigned long long k = kb[idx];
          if ((unsigned)(k >> 40) == pre12)
            atomicAdd(&hist[(int)((k >> 32) & 0xFFull)], 1);
        }
      }
      __syncthreads();
      scan_select(hist, 256, need, tid, chunk, res);
      cutoff32 = (pre12 << 8) | (unsigned)res[0];
      __syncthreads();
    }
  }
  if (tid == 0) s_lcnt = 0;
  __syncthreads();
  const unsigned long long cutkey = (unsigned long long)cutoff32 << 32;
  for (int idx = tid; idx < FG_N * D_N; idx += 256) {
    int c = idx / D_N, r = idx - c * D_N;
    if (r < s_cnts[c]) {
      unsigned long long k = kb[idx];
      if (k >= cutkey) {
        int pos = atomicAdd(&s_lcnt, 1);
        if (pos < 1024) lst[pos] = k;
      }
    }
  }
  __syncthreads();
  const int n = s_lcnt < 1024 ? s_lcnt : 1024;
  const int W = (n <= 256) ? 256 : (n <= 512) ? 512 : 1024;
  for (int i = tid; i < W; i += 256) if (i >= n) lst[i] = 0ULL;
  __syncthreads();
  for (int kk = 2; kk <= W; kk <<= 1) {
    for (int jj = kk >> 1; jj > 0; jj >>= 1) {
      for (int i = tid; i < W; i += 256) {
        int ix = i ^ jj;
        if (ix > i) {
          unsigned long long va = lst[i], vb = lst[ix];
          bool desc = ((i & kk) == 0);
          if (desc ? (va < vb) : (va > vb)) { lst[i] = vb; lst[ix] = va; }
        }
      }
      __syncthreads();
    }
  }
  for (int i = tid; i < D_N; i += 256) {
    int v = -1;
    if (i < npick)
      v = (int)(0xFFFFFFFFu - (unsigned)(lst[i] & 0xFFFFFFFFull));
    pick_flat[b * D_N + i] = v;
  }
}

// ---------------------------------------------------------------------------
// K5: one wave per pick. Lane = fg class; packed u64 (score | ~class)
//     butterfly top-2 reduce reproduces jax top_k tie semantics exactly.
// ---------------------------------------------------------------------------
__global__ __launch_bounds__(256) void k5_out(
    const float* __restrict__ probs_t, const float* __restrict__ boxes,
    const int* __restrict__ topk_anchor, const int* __restrict__ pick_flat,
    float* __restrict__ out)
{
  const int wid  = threadIdx.x >> 6;
  const int lane = threadIdx.x & 63;
  const int pick = blockIdx.x * 4 + wid;        // grid = B_N*D_N/4 blocks
  const int b = pick / D_N;
  float* ob = out + (size_t)pick * 4;
  float* os = out + (size_t)B_N * D_N * 4 + (size_t)pick * 2;
  float* ol = out + (size_t)B_N * D_N * 6 + (size_t)pick * 2;
  const int flat = pick_flat[pick];
  if (flat < 0) {
    if (lane == 0) {
      ob[0] = 0.0f; ob[1] = 0.0f; ob[2] = 0.0f; ob[3] = 0.0f;
      os[0] = 0.0f; os[1] = 0.0f;
      ol[0] = 0.0f; ol[1] = 0.0f;
    }
    return;
  }
  const int c = flat / K_TOP;
  const int r = flat - c * K_TOP;
  const int anchor = topk_anchor[((size_t)b * FG_N + c) * K_TOP + r];
  const float* pp = probs_t + (size_t)b * FG_N * A_N + anchor;

  // per-lane candidates: cc = lane (always < 90? lane<64<90 yes) and lane+64
  unsigned long long hi, lo = 0ULL;
  {
    float p = pp[(size_t)lane * A_N];
    hi = ((unsigned long long)__float_as_uint(p) << 32) | (0xFFFFFFFFu - (unsigned)lane);
  }
  if (lane + 64 < FG_N) {
    float p = pp[(size_t)(lane + 64) * A_N];
    unsigned long long k2 = ((unsigned long long)__float_as_uint(p) << 32) |
                            (0xFFFFFFFFu - (unsigned)(lane + 64));
    if (k2 > hi) { lo = hi; hi = k2; } else lo = k2;
  }
#pragma unroll
  for (int d = 1; d < 64; d <<= 1) {
    unsigned long long oh = __shfl_xor(hi, d, 64);
    unsigned long long ol2 = __shfl_xor(lo, d, 64);
    unsigned long long nh = hi > oh ? hi : oh;
    unsigned long long mn = hi > oh ? oh : hi;
    unsigned long long ml = lo > ol2 ? lo : ol2;
    hi = nh;
    lo = mn > ml ? mn : ml;
  }
  if (lane == 0) {
    float4 bp = *(const float4*)(boxes + ((size_t)b * A_N + anchor) * 4);
    *(float4*)ob = bp;
    unsigned cc1 = 0xFFFFFFFFu - (unsigned)(hi & 0xFFFFFFFFull);
    unsigned cc2 = 0xFFFFFFFFu - (unsigned)(lo & 0xFFFFFFFFull);
    os[0] = __uint_as_float((unsigned)(hi >> 32));
    os[1] = __uint_as_float((unsigned)(lo >> 32));
    ol[0] = (float)(cc1 + 1);
    ol[1] = (float)(cc2 + 1);
  }
}

// ---------------------------------------------------------------------------
extern "C" void kernel_launch(void* const* d_in, const int* in_sizes, int n_in,
                              void* d_out, int out_size, void* d_ws, size_t ws_size,
                              hipStream_t stream)
{
  (void)in_sizes; (void)n_in; (void)out_size; (void)ws_size;
  const float* cls = (const float*)d_in[0];
  const float* reg = (const float*)d_in[1];
  const float* anc = (const float*)d_in[2];

  char* w = (char*)d_ws;
  size_t off = 0;
  auto carve = [&](size_t bytes) -> char* {
    char* p = w + off;
    off += (bytes + 255) & ~(size_t)255;
    return p;
  };
  float* probs_t                = (float*)carve((size_t)B_N * FG_N * A_N * 4);
  float* boxes                  = (float*)carve((size_t)B_N * A_N * 4 * 4);
  int* topk_anchor              = (int*)carve((size_t)NTASK * K_TOP * 4);
  float* topk_score             = (float*)carve((size_t)NTASK * K_TOP * 4);
  int* topk_cnt                 = (int*)carve((size_t)NTASK * 4);
  unsigned long long* kept_key  = (unsigned long long*)carve((size_t)NTASK * D_N * 8);
  int* kept_cnt                 = (int*)carve((size_t)NTASK * 4);
  int* pick_flat                = (int*)carve((size_t)B_N * D_N * 4);

  hipLaunchKernelGGL(k1_softmax_decode, dim3(B_N * K1_NBLK), dim3(K1_APB), 0, stream,
                     cls, reg, anc, probs_t, boxes);
  hipLaunchKernelGGL(k2_topk, dim3(NTASK), dim3(256), 0, stream,
                     probs_t, topk_anchor, topk_score, topk_cnt);
  hipLaunchKernelGGL(k3_nms, dim3(NTASK / 4), dim3(256), 0, stream,
                     boxes, topk_anchor, topk_score, topk_cnt, kept_key, kept_cnt);
  hipLaunchKernelGGL(k4_sel, dim3(B_N), dim3(256), 0, stream,
                     kept_key, kept_cnt, pick_flat);
  hipLaunchKernelGGL(k5_out, dim3(B_N * D_N / 4), dim3(256), 0, stream,
                     probs_t, boxes, topk_anchor, pick_flat, (float*)d_out);
}

// Round 7
// 369.201 us; speedup vs baseline: 1.8954x; 1.0992x over previous
//
#include <hip/hip_runtime.h>
#include <cstdint>
#include <cstddef>

#define B_N   16
#define A_N   8732
#define C_N   91
#define FG_N  90
#define K_TOP 400
#define D_N   200
#define NTASK (B_N * FG_N)   // 1440
#define K1_APB 128           // anchors per block in k1
#define K1_NBLK ((A_N + K1_APB - 1) / K1_APB)   // 69

// ---------------------------------------------------------------------------
// K1: softmax + decode, LDS-staged (coalesced float4 slab load, expf once).
// ---------------------------------------------------------------------------
__global__ __launch_bounds__(128) void k1_softmax_decode(
    const float* __restrict__ cls, const float* __restrict__ reg,
    const float* __restrict__ anc, float* __restrict__ probs_t,
    float* __restrict__ boxes)
{
#pragma clang fp contract(off)
  __shared__ float4 lds4[(K1_APB * C_N + 3) / 4];   // 46.6 KB
  float* lds = (float*)lds4;
  const int bb = blockIdx.x;
  const int b = bb / K1_NBLK;
  const int blk = bb - b * K1_NBLK;
  const int a0 = blk * K1_APB;
  const int nloc = (A_N - a0) < K1_APB ? (A_N - a0) : K1_APB;
  const int tid = threadIdx.x;

  const size_t gbase_f4 = ((size_t)(b * A_N + a0) * C_N) >> 2;
  const size_t TOT_F4 = ((size_t)B_N * A_N * C_N) >> 2;
  const float4* cls4 = (const float4*)cls;
  constexpr int NF4 = (K1_APB * C_N) / 4;           // 2912
  for (int i = tid; i < NF4; i += K1_APB) {
    size_t g = gbase_f4 + i;
    if (g < TOT_F4) lds4[i] = cls4[g];
  }
  __syncthreads();

  if (tid >= nloc) return;
  const int a = a0 + tid;
  const int tg = b * A_N + a;
  float* lg = lds + tid * C_N;

  float m = lg[0];
  for (int c = 1; c < C_N; ++c) m = fmaxf(m, lg[c]);
  float s = 0.0f;
  for (int c = 0; c < C_N; ++c) {
    float e = expf(lg[c] - m);
    s += e;
    lg[c] = e;
  }
  for (int c = 1; c < C_N; ++c)
    probs_t[((size_t)b * FG_N + (c - 1)) * A_N + a] = lg[c] / s;

  float4 rl = *(const float4*)(reg + (size_t)tg * 4);
  float4 an = *(const float4*)(anc + (size_t)a * 4);
  float wa = an.z - an.x;
  float ha = an.w - an.y;
  float cxa = an.x + 0.5f * wa;
  float cya = an.y + 0.5f * ha;
  float dx = rl.x / 10.0f;
  float dy = rl.y / 10.0f;
  const float clipv = 4.135166556742356f;   // log(1000/16)
  float dw = fminf(rl.z / 5.0f, clipv);
  float dh = fminf(rl.w / 5.0f, clipv);
  float t1 = dx * wa;  float cx = t1 + cxa;
  float t2 = dy * ha;  float cy = t2 + cya;
  float w = expf(dw) * wa;
  float h = expf(dh) * ha;
  float4 out;
  out.x = fminf(fmaxf(cx - 0.5f * w, 0.0f), 300.0f);
  out.y = fminf(fmaxf(cy - 0.5f * h, 0.0f), 300.0f);
  out.z = fminf(fmaxf(cx + 0.5f * w, 0.0f), 300.0f);
  out.w = fminf(fmaxf(cy + 0.5f * h, 0.0f), 300.0f);
  *(float4*)(boxes + (size_t)tg * 4) = out;
}

// ---------------------------------------------------------------------------
// shared helper: descending rank-select over a 256-chunked histogram
// ---------------------------------------------------------------------------
__device__ __forceinline__ void scan_select(int* hist, int nbins, int need,
                                            int tid, int* chunk, int* res)
{
  int per = nbins >> 8;            // 4096 -> 16, 256 -> 1
  int s = 0;
  for (int i = 0; i < per; ++i) s += hist[tid * per + i];
  chunk[tid] = s;
  __syncthreads();
  if (tid == 0) {
    int cum = 0;
    for (int t2 = 255; t2 >= 0; --t2) { int v = chunk[t2]; chunk[t2] = cum; cum += v; }
  }
  __syncthreads();
  int cum = chunk[tid];            // count in strictly-higher chunks
  for (int i = per - 1; i >= 0; --i) {
    int bn = tid * per + i;
    int h = hist[bn];
    if (cum < need && need <= cum + h) { res[0] = bn; res[1] = cum; }
    cum += h;
  }
  __syncthreads();
}

// ---------------------------------------------------------------------------
// K2: exact top-400 per (image, fg-class). Common path: single global pass
//     into 1024-slot LDS buffer + bitonic sort; radix-select fallback only
//     when count > 1024.
// ---------------------------------------------------------------------------
__global__ __launch_bounds__(256) void k2_topk(
    const float* __restrict__ probs_t, int* __restrict__ topk_anchor,
    float* __restrict__ topk_score, int* __restrict__ topk_cnt)
{
  __shared__ int hist[4096];
  __shared__ int chunk[256];
  __shared__ int res[2];
  __shared__ int s_lcnt;
  __shared__ unsigned long long lst[1024];
  const int task = blockIdx.x;
  const int tid = threadIdx.x;
  const float* sc = probs_t + (size_t)task * A_N;

  if (tid == 0) s_lcnt = 0;
  __syncthreads();
  for (int a = tid; a < A_N; a += 256) {
    float p = sc[a];
    if (p > 0.01f) {
      unsigned k = __float_as_uint(p);
      int pos = atomicAdd(&s_lcnt, 1);
      if (pos < 1024)
        lst[pos] = ((unsigned long long)k << 32) | (unsigned)(0xFFFFFFFFu - (unsigned)a);
    }
  }
  __syncthreads();
  const int total = s_lcnt;
  const int ksel = total < K_TOP ? total : K_TOP;
  int n;
  if (total <= 1024) {
    n = total;
    __syncthreads();
  } else {
    for (int i = tid; i < 4096; i += 256) hist[i] = 0;
    __syncthreads();
    for (int a = tid; a < A_N; a += 256) {
      float p = sc[a];
      if (p > 0.01f) atomicAdd(&hist[__float_as_uint(p) >> 20], 1);
    }
    __syncthreads();
    int need = K_TOP;
    scan_select(hist, 4096, need, tid, chunk, res);
    const unsigned b1 = (unsigned)res[0];
    const int above1 = res[1];
    const int in1 = hist[b1];
    __syncthreads();
    unsigned cutoff;
    if (above1 + in1 <= 1024) {
      cutoff = b1 << 20;
    } else {
      need -= above1;
      for (int i = tid; i < 4096; i += 256) hist[i] = 0;
      __syncthreads();
      for (int a = tid; a < A_N; a += 256) {
        float p = sc[a];
        if (p > 0.01f) {
          unsigned k = __float_as_uint(p);
          if ((k >> 20) == b1) atomicAdd(&hist[(k >> 8) & 0xFFFu], 1);
        }
      }
      __syncthreads();
      scan_select(hist, 4096, need, tid, chunk, res);
      const unsigned b2 = (unsigned)res[0];
      need -= res[1];
      const unsigned pre12 = (b1 << 12) | b2;
      __syncthreads();
      hist[tid] = 0;
      __syncthreads();
      for (int a = tid; a < A_N; a += 256) {
        float p = sc[a];
        if (p > 0.01f) {
          unsigned k = __float_as_uint(p);
          if ((k >> 8) == pre12) atomicAdd(&hist[k & 0xFFu], 1);
        }
      }
      __syncthreads();
      scan_select(hist, 256, need, tid, chunk, res);
      cutoff = (pre12 << 8) | (unsigned)res[0];
      __syncthreads();
    }
    if (tid == 0) s_lcnt = 0;
    __syncthreads();
    for (int a = tid; a < A_N; a += 256) {
      float p = sc[a];
      if (p > 0.01f) {
        unsigned k = __float_as_uint(p);
        if (k >= cutoff) {
          int pos = atomicAdd(&s_lcnt, 1);
          if (pos < 1024)
            lst[pos] = ((unsigned long long)k << 32) | (unsigned)(0xFFFFFFFFu - (unsigned)a);
        }
      }
    }
    __syncthreads();
    n = s_lcnt < 1024 ? s_lcnt : 1024;
  }

  const int W = (n <= 512) ? 512 : 1024;
  for (int i = tid; i < W; i += 256) if (i >= n) lst[i] = 0ULL;
  __syncthreads();
  for (int kk = 2; kk <= W; kk <<= 1) {
    for (int jj = kk >> 1; jj > 0; jj >>= 1) {
      for (int i = tid; i < W; i += 256) {
        int ix = i ^ jj;
        if (ix > i) {
          unsigned long long va = lst[i], vb = lst[ix];
          bool desc = ((i & kk) == 0);
          if (desc ? (va < vb) : (va > vb)) { lst[i] = vb; lst[ix] = va; }
        }
      }
      __syncthreads();
    }
  }
  for (int r = tid; r < K_TOP; r += 256) {
    int anchor = 0;
    float scv = -1.0f;
    if (r < ksel) {
      unsigned long long v = lst[r];
      anchor = (int)(0xFFFFFFFFu - (unsigned)(v & 0xFFFFFFFFull));
      scv = __uint_as_float((unsigned)(v >> 32));
    }
    topk_anchor[(size_t)task * K_TOP + r] = anchor;
    topk_score[(size_t)task * K_TOP + r] = scv;
  }
  if (tid == 0) topk_cnt[task] = ksel;
}

// ---------------------------------------------------------------------------
// K3: chunked greedy NMS, one BLOCK (4 waves) per (image,class).
//     Phase (a) kept-test split across the 4 waves (wave w tests kept k ≡ w
//     mod 4; ballots OR'd via LDS). Division fallback behind a wave-uniform
//     __ballot guard so the IEEE divide is skipped when no lane is in the
//     1.5e-6 ambiguous band (virtually always). Phase (b) resolve + append
//     on wave 0 as before. Result identical to the serial greedy; IoU
//     decisions bit-match the reference.
// ---------------------------------------------------------------------------
__global__ __launch_bounds__(256) void k3_nms(
    const float* __restrict__ boxes, const int* __restrict__ topk_anchor,
    const float* __restrict__ topk_score, const int* __restrict__ topk_cnt,
    unsigned long long* __restrict__ kept_key, int* __restrict__ kept_cnt)
{
#pragma clang fp contract(off)
  __shared__ float4 keptb[D_N];                 // 3.2 KB
  __shared__ float  kepta[D_N];
  __shared__ int    keptr[D_N];
  __shared__ unsigned long long s_supm[4];
  __shared__ int s_nk;
  const int task = blockIdx.x;                  // grid = NTASK
  const int wid  = threadIdx.x >> 6;
  const int lane = threadIdx.x & 63;
  const int b = task / FG_N;
  const int c = task - b * FG_N;
  const float off = (float)(c + 1) * 302.0f;
  const int cnt = topk_cnt[task];
  const int* ta = topk_anchor + (size_t)task * K_TOP;
  const float* ts = topk_score + (size_t)task * K_TOP;
  const float* bx = boxes + (size_t)b * (A_N * 4);

  if (threadIdx.x == 0) s_nk = 0;
  __syncthreads();

  // prefetch chunk 0 (each wave keeps its own copy; same addrs -> L1 hits)
  float4 nxt = make_float4(0.0f, 0.0f, 0.0f, 0.0f);
  if (lane < cnt) nxt = *(const float4*)(bx + (size_t)ta[lane] * 4);

  for (int c0 = 0; c0 < cnt; c0 += 64) {
    float4 cur = nxt;
    int nidx = c0 + 64 + lane;
    if (nidx < cnt) nxt = *(const float4*)(bx + (size_t)ta[nidx] * 4);
    const bool validc = (c0 + lane) < cnt;
    cur.x += off; cur.y += off; cur.z += off; cur.w += off;
    const float area = (cur.z - cur.x) * (cur.w - cur.y);
    const int nk = s_nk;                        // stable since last barrier

    // (a) kept-test, strided across the block's 4 waves
    bool sup = !validc;
    for (int k = wid; k < nk; k += 4) {
      float4 kb = keptb[k];                     // broadcast read
      float  ka = kepta[k];
      float ix1 = fmaxf(cur.x, kb.x);
      float iy1 = fmaxf(cur.y, kb.y);
      float ix2 = fminf(cur.z, kb.z);
      float iy2 = fminf(cur.w, kb.w);
      float inter = fmaxf(ix2 - ix1, 0.0f) * fmaxf(iy2 - iy1, 0.0f);
      float denom = ka + area - inter + 1e-9f;
      float thr = 0.45f * denom;
      bool s_sup = inter > thr;
      bool amb = fabsf(inter - thr) <= 1.5e-6f * thr;
      if (__ballot(amb)) {                      // wave-uniform: skip divide
        if (amb) s_sup = (inter / denom) > 0.45f;   // exact ref expression
      }
      sup = sup || s_sup;
    }
    s_supm[wid] = __ballot(sup);
    __syncthreads();

    if (wid == 0) {
      // (b) intra-chunk resolve: visit survivors in order, suppress forward
      unsigned long long todo =
          ~(s_supm[0] | s_supm[1] | s_supm[2] | s_supm[3]);
      unsigned long long surv = 0ULL;
      int ns = 0;
      const int room = D_N - nk;
      while (todo) {
        if (ns == room) break;
        int j = __ffsll((unsigned long long)todo) - 1;
        surv |= 1ULL << j;
        ++ns;
        todo &= ~(1ULL << j);
        float jx1 = __shfl(cur.x, j);
        float jy1 = __shfl(cur.y, j);
        float jx2 = __shfl(cur.z, j);
        float jy2 = __shfl(cur.w, j);
        float ja  = __shfl(area, j);
        float ix1 = fmaxf(jx1, cur.x);
        float iy1 = fmaxf(jy1, cur.y);
        float ix2 = fminf(jx2, cur.z);
        float iy2 = fminf(jy2, cur.w);
        float inter = fmaxf(ix2 - ix1, 0.0f) * fmaxf(iy2 - iy1, 0.0f);
        float denom = ja + area - inter + 1e-9f;
        float thr = 0.45f * denom;
        bool s_sup = inter > thr;
        bool amb = fabsf(inter - thr) <= 1.5e-6f * thr;
        if (__ballot(amb)) {
          if (amb) s_sup = (inter / denom) > 0.45f;
        }
        unsigned long long supj = __ballot(s_sup);
        supj &= ~(1ULL << j);                   // self-IoU = 1, mask out
        todo &= ~supj;
      }
      // (c) parallel append, order = lane order = score order
      if ((surv >> lane) & 1ULL) {
        int my = nk + __popcll(surv & ((1ULL << lane) - 1ULL));
        keptb[my] = cur;
        kepta[my] = area;
        keptr[my] = c0 + lane;
      }
      if (lane == 0) s_nk = nk + ns;
    }
    __syncthreads();
    if (s_nk >= D_N) break;
  }

  const int nkf = s_nk;
  for (int k = threadIdx.x; k < nkf; k += 256) {
    int r = keptr[k];
    unsigned sb = __float_as_uint(ts[r]);
    kept_key[(size_t)task * D_N + k] =
        ((unsigned long long)sb << 32) |
        (unsigned)(0xFFFFFFFFu - (unsigned)(c * K_TOP + r));
  }
  if (threadIdx.x == 0) kept_cnt[task] = nkf;
}

// ---------------------------------------------------------------------------
// K4: per-image global pick selection = parallel top-200 of survivor keys
//     (suppression already applied per class; picks don't interact).
// ---------------------------------------------------------------------------
__global__ __launch_bounds__(256) void k4_sel(
    const unsigned long long* __restrict__ kept_key,
    const int* __restrict__ kept_cnt, int* __restrict__ pick_flat)
{
  __shared__ int hist[4096];
  __shared__ int chunk[256];
  __shared__ int res[2];
  __shared__ int s_lcnt;
  __shared__ int s_cnts[FG_N];
  __shared__ unsigned long long lst[1024];
  const int b = blockIdx.x;
  const int tid = threadIdx.x;
  const unsigned long long* kb = kept_key + (size_t)b * FG_N * D_N;

  if (tid < FG_N) s_cnts[tid] = kept_cnt[b * FG_N + tid];
  for (int i = tid; i < 4096; i += 256) hist[i] = 0;
  if (tid == 0) s_lcnt = 0;
  __syncthreads();

  for (int idx = tid; idx < FG_N * D_N; idx += 256) {
    int c = idx / D_N, r = idx - c * D_N;
    if (r < s_cnts[c]) {
      unsigned long long k = kb[idx];
      atomicAdd(&hist[(int)(k >> 52)], 1);
      atomicAdd(&s_lcnt, 1);
    }
  }
  __syncthreads();
  const int total = s_lcnt;
  const int npick = total < D_N ? total : D_N;
  unsigned cutoff32 = 1u;
  if (total > D_N) {
    int need = D_N;
    scan_select(hist, 4096, need, tid, chunk, res);
    const unsigned b1 = (unsigned)res[0];
    const int above1 = res[1];
    const int in1 = hist[b1];
    __syncthreads();
    if (above1 + in1 <= 1024) {
      cutoff32 = b1 << 20;
    } else {
      need -= above1;
      for (int i = tid; i < 4096; i += 256) hist[i] = 0;
      __syncthreads();
      for (int idx = tid; idx < FG_N * D_N; idx += 256) {
        int c = idx / D_N, r = idx - c * D_N;
        if (r < s_cnts[c]) {
          unsigned long long k = kb[idx];
          if ((unsigned)(k >> 52) == b1)
            atomicAdd(&hist[(int)((k >> 40) & 0xFFFull)], 1);
        }
      }
      __syncthreads();
      scan_select(hist, 4096, need, tid, chunk, res);
      const unsigned b2 = (unsigned)res[0];
      need -= res[1];
      const unsigned pre12 = (b1 << 12) | b2;
      __syncthreads();
      hist[tid] = 0;
      __syncthreads();
      for (int idx = tid; idx < FG_N * D_N; idx += 256) {
        int c = idx / D_N, r = idx - c * D_N;
        if (r < s_cnts[c]) {
          unsigned long long k = kb[idx];
          if ((unsigned)(k >> 40) == pre12)
            atomicAdd(&hist[(int)((k >> 32) & 0xFFull)], 1);
        }
      }
      __syncthreads();
      scan_select(hist, 256, need, tid, chunk, res);
      cutoff32 = (pre12 << 8) | (unsigned)res[0];
      __syncthreads();
    }
  }
  if (tid == 0) s_lcnt = 0;
  __syncthreads();
  const unsigned long long cutkey = (unsigned long long)cutoff32 << 32;
  for (int idx = tid; idx < FG_N * D_N; idx += 256) {
    int c = idx / D_N, r = idx - c * D_N;
    if (r < s_cnts[c]) {
      unsigned long long k = kb[idx];
      if (k >= cutkey) {
        int pos = atomicAdd(&s_lcnt, 1);
        if (pos < 1024) lst[pos] = k;
      }
    }
  }
  __syncthreads();
  const int n = s_lcnt < 1024 ? s_lcnt : 1024;
  const int W = (n <= 256) ? 256 : (n <= 512) ? 512 : 1024;
  for (int i = tid; i < W; i += 256) if (i >= n) lst[i] = 0ULL;
  __syncthreads();
  for (int kk = 2; kk <= W; kk <<= 1) {
    for (int jj = kk >> 1; jj > 0; jj >>= 1) {
      for (int i = tid; i < W; i += 256) {
        int ix = i ^ jj;
        if (ix > i) {
          unsigned long long va = lst[i], vb = lst[ix];
          bool desc = ((i & kk) == 0);
          if (desc ? (va < vb) : (va > vb)) { lst[i] = vb; lst[ix] = va; }
        }
      }
      __syncthreads();
    }
  }
  for (int i = tid; i < D_N; i += 256) {
    int v = -1;
    if (i < npick)
      v = (int)(0xFFFFFFFFu - (unsigned)(lst[i] & 0xFFFFFFFFull));
    pick_flat[b * D_N + i] = v;
  }
}

// ---------------------------------------------------------------------------
// K5: one wave per pick. Lane = fg class; packed u64 (score | ~class)
//     butterfly top-2 reduce reproduces jax top_k tie semantics exactly.
// ---------------------------------------------------------------------------
__global__ __launch_bounds__(256) void k5_out(
    const float* __restrict__ probs_t, const float* __restrict__ boxes,
    const int* __restrict__ topk_anchor, const int* __restrict__ pick_flat,
    float* __restrict__ out)
{
  const int wid  = threadIdx.x >> 6;
  const int lane = threadIdx.x & 63;
  const int pick = blockIdx.x * 4 + wid;        // grid = B_N*D_N/4 blocks
  const int b = pick / D_N;
  float* ob = out + (size_t)pick * 4;
  float* os = out + (size_t)B_N * D_N * 4 + (size_t)pick * 2;
  float* ol = out + (size_t)B_N * D_N * 6 + (size_t)pick * 2;
  const int flat = pick_flat[pick];
  if (flat < 0) {
    if (lane == 0) {
      ob[0] = 0.0f; ob[1] = 0.0f; ob[2] = 0.0f; ob[3] = 0.0f;
      os[0] = 0.0f; os[1] = 0.0f;
      ol[0] = 0.0f; ol[1] = 0.0f;
    }
    return;
  }
  const int c = flat / K_TOP;
  const int r = flat - c * K_TOP;
  const int anchor = topk_anchor[((size_t)b * FG_N + c) * K_TOP + r];
  const float* pp = probs_t + (size_t)b * FG_N * A_N + anchor;

  unsigned long long hi, lo = 0ULL;
  {
    float p = pp[(size_t)lane * A_N];
    hi = ((unsigned long long)__float_as_uint(p) << 32) | (0xFFFFFFFFu - (unsigned)lane);
  }
  if (lane + 64 < FG_N) {
    float p = pp[(size_t)(lane + 64) * A_N];
    unsigned long long k2 = ((unsigned long long)__float_as_uint(p) << 32) |
                            (0xFFFFFFFFu - (unsigned)(lane + 64));
    if (k2 > hi) { lo = hi; hi = k2; } else lo = k2;
  }
#pragma unroll
  for (int d = 1; d < 64; d <<= 1) {
    unsigned long long oh = __shfl_xor(hi, d, 64);
    unsigned long long ol2 = __shfl_xor(lo, d, 64);
    unsigned long long nh = hi > oh ? hi : oh;
    unsigned long long mn = hi > oh ? oh : hi;
    unsigned long long ml = lo > ol2 ? lo : ol2;
    hi = nh;
    lo = mn > ml ? mn : ml;
  }
  if (lane == 0) {
    float4 bp = *(const float4*)(boxes + ((size_t)b * A_N + anchor) * 4);
    *(float4*)ob = bp;
    unsigned cc1 = 0xFFFFFFFFu - (unsigned)(hi & 0xFFFFFFFFull);
    unsigned cc2 = 0xFFFFFFFFu - (unsigned)(lo & 0xFFFFFFFFull);
    os[0] = __uint_as_float((unsigned)(hi >> 32));
    os[1] = __uint_as_float((unsigned)(lo >> 32));
    ol[0] = (float)(cc1 + 1);
    ol[1] = (float)(cc2 + 1);
  }
}

// ---------------------------------------------------------------------------
extern "C" void kernel_launch(void* const* d_in, const int* in_sizes, int n_in,
                              void* d_out, int out_size, void* d_ws, size_t ws_size,
                              hipStream_t stream)
{
  (void)in_sizes; (void)n_in; (void)out_size; (void)ws_size;
  const float* cls = (const float*)d_in[0];
  const float* reg = (const float*)d_in[1];
  const float* anc = (const float*)d_in[2];

  char* w = (char*)d_ws;
  size_t off = 0;
  auto carve = [&](size_t bytes) -> char* {
    char* p = w + off;
    off += (bytes + 255) & ~(size_t)255;
    return p;
  };
  float* probs_t                = (float*)carve((size_t)B_N * FG_N * A_N * 4);
  float* boxes                  = (float*)carve((size_t)B_N * A_N * 4 * 4);
  int* topk_anchor              = (int*)carve((size_t)NTASK * K_TOP * 4);
  float* topk_score             = (float*)carve((size_t)NTASK * K_TOP * 4);
  int* topk_cnt                 = (int*)carve((size_t)NTASK * 4);
  unsigned long long* kept_key  = (unsigned long long*)carve((size_t)NTASK * D_N * 8);
  int* kept_cnt                 = (int*)carve((size_t)NTASK * 4);
  int* pick_flat                = (int*)carve((size_t)B_N * D_N * 4);

  hipLaunchKernelGGL(k1_softmax_decode, dim3(B_N * K1_NBLK), dim3(K1_APB), 0, stream,
                     cls, reg, anc, probs_t, boxes);
  hipLaunchKernelGGL(k2_topk, dim3(NTASK), dim3(256), 0, stream,
                     probs_t, topk_anchor, topk_score, topk_cnt);
  hipLaunchKernelGGL(k3_nms, dim3(NTASK), dim3(256), 0, stream,
                     boxes, topk_anchor, topk_score, topk_cnt, kept_key, kept_cnt);
  hipLaunchKernelGGL(k4_sel, dim3(B_N), dim3(256), 0, stream,
                     kept_key, kept_cnt, pick_flat);
  hipLaunchKernelGGL(k5_out, dim3(B_N * D_N / 4), dim3(256), 0, stream,
                     probs_t, boxes, topk_anchor, pick_flat, (float*)d_out);
}